// Round 3
// baseline (4340.767 us; speedup 1.0000x reference)
//
#include <hip/hip_runtime.h>

#define NEG_SLOPE 0.2f
#define NG 8

__device__ __forceinline__ float lrelu(float x) { return x > 0.f ? x : NEG_SLOPE * x; }
__device__ __forceinline__ float eluf(float x) { return x > 0.f ? x : expm1f(x); }
// monotone float<->uint encoding for atomicMax on floats
__device__ __forceinline__ unsigned enc(float x) {
    unsigned u = __float_as_uint(x);
    return (u & 0x80000000u) ? ~u : (u | 0x80000000u);
}
__device__ __forceinline__ float dec(unsigned k) {
    return (k & 0x80000000u) ? __uint_as_float(k & 0x7fffffffu) : __uint_as_float(~k);
}

// xw1h[N,64] = x[N,256] @ W1[:, head*64 : head*64+64]   (f32)
__global__ __launch_bounds__(256) void k_gemm1h(const float* __restrict__ x,
                                                const float* __restrict__ W1,
                                                int head, float* __restrict__ xw1h, int N) {
    __shared__ float As[16][256];
    int r0 = blockIdx.x * 16;
    int c = threadIdx.x & 63, rq = threadIdx.x >> 6;
    for (int i = threadIdx.x; i < 1024; i += 256) {      // 16 rows x 64 float4
        int r = i >> 6, k4 = (i & 63) << 2;
        float4 v = (r0 + r < N) ? *(const float4*)(x + (size_t)(r0 + r) * 256 + k4)
                                : make_float4(0.f, 0.f, 0.f, 0.f);
        As[r][k4] = v.x; As[r][k4 + 1] = v.y; As[r][k4 + 2] = v.z; As[r][k4 + 3] = v.w;
    }
    __syncthreads();
    float acc[4] = {0.f, 0.f, 0.f, 0.f};
    const float* Wc = W1 + head * 64 + c;
    #pragma unroll 4
    for (int k = 0; k < 256; k++) {
        float w = Wc[(size_t)k * 256];
        #pragma unroll
        for (int t = 0; t < 4; t++) acc[t] += As[rq + 4 * t][k] * w;
    }
    #pragma unroll
    for (int t = 0; t < 4; t++) {
        int r = r0 + rq + 4 * t;
        if (r < N) xw1h[(size_t)r * 64 + c] = acc[t];
    }
}

// al/ar per node from one 64-wide feature block + seed segment-max with self-loop
__global__ __launch_bounds__(256) void k_alar(const float* __restrict__ xw,
                                              const float* __restrict__ a_s,
                                              const float* __restrict__ a_d,
                                              float* __restrict__ al, float* __restrict__ ar,
                                              unsigned* __restrict__ mkey, int N) {
    int n = blockIdx.x * 256 + threadIdx.x;
    if (n >= N) return;
    const float* row = xw + (size_t)n * 64;
    float sl = 0.f, sr = 0.f;
    #pragma unroll 8
    for (int c = 0; c < 64; c++) {
        float v = row[c];
        sl += v * a_s[c];
        sr += v * a_d[c];
    }
    al[n] = sl; ar[n] = sr;
    mkey[n] = enc(lrelu(sl + sr));   // self-loop seeds the segment max
}

__global__ __launch_bounds__(256) void k_edgemax(const int* __restrict__ ei,
                                                 const float* __restrict__ al,
                                                 const float* __restrict__ ar,
                                                 unsigned* __restrict__ mkey, int E) {
    int e = blockIdx.x * 256 + threadIdx.x;
    if (e >= E) return;
    int s = ei[e], d = ei[E + e];
    atomicMax(&mkey[d], enc(lrelu(al[s] + ar[d])));
}

// decode max key -> float m (in place), init denom with self-loop term
__global__ __launch_bounds__(256) void k_denominit(const float* __restrict__ al,
                                                   const float* __restrict__ ar,
                                                   unsigned* __restrict__ mkey,
                                                   float* __restrict__ denom, int N) {
    int n = blockIdx.x * 256 + threadIdx.x;
    if (n >= N) return;
    float m = dec(mkey[n]);
    ((float*)mkey)[n] = m;
    denom[n] = expf(lrelu(al[n] + ar[n]) - m);
}

__global__ __launch_bounds__(256) void k_edgesum(const int* __restrict__ ei,
                                                 const float* __restrict__ al,
                                                 const float* __restrict__ ar,
                                                 const float* __restrict__ mf,
                                                 float* __restrict__ denom, int E) {
    int e = blockIdx.x * 256 + threadIdx.x;
    if (e >= E) return;
    int s = ei[e], d = ei[E + e];
    atomicAdd(&denom[d], expf(lrelu(al[s] + ar[d]) - mf[d]));
}

// self-loop contribution; also initializes outb (ws is poisoned each call)
__global__ __launch_bounds__(256) void k_selfscatter(const float* __restrict__ xw,
                                                     const float* __restrict__ al,
                                                     const float* __restrict__ ar,
                                                     const float* __restrict__ mf,
                                                     const float* __restrict__ denom,
                                                     float* __restrict__ outb, int N) {
    int t = blockIdx.x * 256 + threadIdx.x;
    if (t >= N * 16) return;
    int n = t >> 4; int c4 = (t & 15) << 2;
    float alpha = expf(lrelu(al[n] + ar[n]) - mf[n]) / denom[n];
    float4 v = *(const float4*)(xw + (size_t)n * 64 + c4);
    float4 o; o.x = alpha * v.x; o.y = alpha * v.y; o.z = alpha * v.z; o.w = alpha * v.w;
    *(float4*)(outb + (size_t)n * 64 + c4) = o;
}

// 16 lanes per edge: gather xw[src] row, scale by alpha, atomic-add into outb[dst]
__global__ __launch_bounds__(256) void k_edgescatter(const int* __restrict__ ei,
                                                     const float* __restrict__ xw,
                                                     const float* __restrict__ al,
                                                     const float* __restrict__ ar,
                                                     const float* __restrict__ mf,
                                                     const float* __restrict__ denom,
                                                     float* __restrict__ outb, int E) {
    int g = (blockIdx.x * 256 + threadIdx.x) >> 4;
    int l = threadIdx.x & 15;
    if (g >= E) return;
    int s = ei[g], d = ei[E + g];
    float alpha = expf(lrelu(al[s] + ar[d]) - mf[d]) / denom[d];
    int c4 = l << 2;
    float4 v = *(const float4*)(xw + (size_t)s * 64 + c4);
    float* ob = outb + (size_t)d * 64 + c4;
    atomicAdd(ob + 0, alpha * v.x);
    atomicAdd(ob + 1, alpha * v.y);
    atomicAdd(ob + 2, alpha * v.z);
    atomicAdd(ob + 3, alpha * v.w);
}

// xw2[N,64] (+)= elu(out1h + b1[head]) @ W2[head*64 : head*64+64, :]
__global__ __launch_bounds__(256) void k_gemm2acc(const float* __restrict__ out1h,
                                                  const float* __restrict__ b1, int head,
                                                  const float* __restrict__ W2,
                                                  float* __restrict__ xw2, int N, int first) {
    __shared__ float Hs[16][64];
    int r0 = blockIdx.x * 16;
    int j = threadIdx.x & 63, rq = threadIdx.x >> 6;
    {
        int r = threadIdx.x >> 4, c4 = (threadIdx.x & 15) << 2;  // 256 threads x float4 = 16x64
        float4 v = (r0 + r < N) ? *(const float4*)(out1h + (size_t)(r0 + r) * 64 + c4)
                                : make_float4(0.f, 0.f, 0.f, 0.f);
        Hs[r][c4]     = eluf(v.x + b1[head * 64 + c4]);
        Hs[r][c4 + 1] = eluf(v.y + b1[head * 64 + c4 + 1]);
        Hs[r][c4 + 2] = eluf(v.z + b1[head * 64 + c4 + 2]);
        Hs[r][c4 + 3] = eluf(v.w + b1[head * 64 + c4 + 3]);
    }
    __syncthreads();
    float acc[4] = {0.f, 0.f, 0.f, 0.f};
    const float* Wr = W2 + (size_t)head * 64 * 64 + j;
    #pragma unroll 4
    for (int c = 0; c < 64; c++) {
        float w = Wr[(size_t)c * 64];
        #pragma unroll
        for (int t = 0; t < 4; t++) acc[t] += Hs[rq + 4 * t][c] * w;
    }
    #pragma unroll
    for (int t = 0; t < 4; t++) {
        int r = r0 + rq + 4 * t;
        if (r < N) {
            size_t o = (size_t)r * 64 + j;
            xw2[o] = first ? acc[t] : (xw2[o] + acc[t]);
        }
    }
}

// bias + ELU in place (keep f32 for pooling) + write f32 h to d_out
__global__ __launch_bounds__(256) void k_elu2(float* __restrict__ out2,
                                              const float* __restrict__ b2,
                                              float* __restrict__ hout, int N) {
    int t = blockIdx.x * 256 + threadIdx.x;
    if (t >= N * 16) return;
    int n = t >> 4; int c4 = (t & 15) << 2;
    float4 v = *(float4*)(out2 + (size_t)n * 64 + c4);
    v.x = eluf(v.x + b2[c4 + 0]);
    v.y = eluf(v.y + b2[c4 + 1]);
    v.z = eluf(v.z + b2[c4 + 2]);
    v.w = eluf(v.w + b2[c4 + 3]);
    *(float4*)(out2 + (size_t)n * 64 + c4) = v;
    *(float4*)(hout + (size_t)n * 64 + c4) = v;
}

// one wave per 256-node chunk; batch is sorted -> run-length accumulate
__global__ __launch_bounds__(256) void k_pool(const float* __restrict__ h2,
                                              const int* __restrict__ batch,
                                              float* __restrict__ pooled,
                                              float* __restrict__ cnt, int N) {
    int wave = (blockIdx.x * 256 + threadIdx.x) >> 6;
    int lane = threadIdx.x & 63;
    int n0 = wave * 256;
    if (n0 >= N) return;
    int n1 = min(n0 + 256, N);
    float acc = 0.f; int cl = 0;
    int curg = batch[n0];
    for (int n = n0; n < n1; n++) {
        int g = batch[n];
        if (g != curg) {
            atomicAdd(&pooled[curg * 64 + lane], acc);
            if (lane == 0) atomicAdd(&cnt[curg], (float)cl);
            acc = 0.f; cl = 0; curg = g;
        }
        acc += h2[(size_t)n * 64 + lane];
        cl++;
    }
    atomicAdd(&pooled[curg * 64 + lane], acc);
    if (lane == 0) atomicAdd(&cnt[curg], (float)cl);
}

__global__ __launch_bounds__(64) void k_logits(const float* __restrict__ pooled,
                                               const float* __restrict__ cnt,
                                               const float* __restrict__ fcW,
                                               const float* __restrict__ fcb,
                                               float* __restrict__ out) {
    int t = threadIdx.x;
    if (t >= NG * 2) return;
    int g = t >> 1, o = t & 1;
    float invc = 1.f / fmaxf(cnt[g], 1.f);
    float s = 0.f;
    for (int c = 0; c < 64; c++)
        s += pooled[g * 64 + c] * invc * fcW[c * 2 + o];
    s += fcb[o];
    out[g * 2 + o] = s;
}

extern "C" void kernel_launch(void* const* d_in, const int* in_sizes, int n_in,
                              void* d_out, int out_size, void* d_ws, size_t ws_size,
                              hipStream_t stream) {
    const float* x     = (const float*)d_in[0];
    const int*   ei    = (const int*)d_in[1];
    const int*   batch = (const int*)d_in[2];
    const float* W1    = (const float*)d_in[3];
    const float* as1   = (const float*)d_in[4];
    const float* ad1   = (const float*)d_in[5];
    const float* b1    = (const float*)d_in[6];
    const float* W2    = (const float*)d_in[7];
    const float* as2   = (const float*)d_in[8];
    const float* ad2   = (const float*)d_in[9];
    const float* b2v   = (const float*)d_in[10];
    const float* fcW   = (const float*)d_in[11];
    const float* fcb   = (const float*)d_in[12];
    float* out = (float*)d_out;

    const int N = in_sizes[2];       // 50000
    const int E = in_sizes[1] / 2;   // 800000
    const size_t nv = (size_t)N * 64;

    // workspace layout (f32 elements); peak ~= 3*nv + 4*N + 520 floats ~= 39.4 MB
    float* ws = (float*)d_ws;
    float*    xw1h  = ws;                 // nv (reused as out2 in layer 2)
    float*    out1h = ws + nv;            // nv
    float*    xw2   = ws + 2 * nv;        // nv
    float*    al    = ws + 3 * nv;        // N
    float*    ar    = ws + 3 * nv + N;    // N
    unsigned* mkey  = (unsigned*)(ws + 3 * nv + 2 * (size_t)N);
    float*    mf    = ws + 3 * nv + 2 * (size_t)N;
    float*    denom = ws + 3 * nv + 3 * (size_t)N;
    float*    pooled= ws + 3 * nv + 4 * (size_t)N;  // 512
    float*    cnt   = pooled + NG * 64;             // 8
    float*    out2  = xw1h;

    const int gN   = (N + 255) / 256;
    const int gE   = (E + 255) / 256;
    const int gN16 = (N * 16 + 255) / 256;
    const int gE16 = (E * 16 + 255) / 256;
    const int gT   = (N + 15) / 16;

    // ---- layer 1, one head at a time; fused elu+GEMM2 accumulation ----
    for (int h = 0; h < 4; h++) {
        k_gemm1h<<<gT, 256, 0, stream>>>(x, W1, h, xw1h, N);
        k_alar<<<gN, 256, 0, stream>>>(xw1h, as1 + h * 64, ad1 + h * 64, al, ar, mkey, N);
        k_edgemax<<<gE, 256, 0, stream>>>(ei, al, ar, mkey, E);
        k_denominit<<<gN, 256, 0, stream>>>(al, ar, mkey, denom, N);
        k_edgesum<<<gE, 256, 0, stream>>>(ei, al, ar, mf, denom, E);
        k_selfscatter<<<gN16, 256, 0, stream>>>(xw1h, al, ar, mf, denom, out1h, N);
        k_edgescatter<<<gE16, 256, 0, stream>>>(ei, xw1h, al, ar, mf, denom, out1h, E);
        k_gemm2acc<<<gT, 256, 0, stream>>>(out1h, b1, h, W2, xw2, N, h == 0);
    }

    // ---- layer 2 (single head) ----
    k_alar<<<gN, 256, 0, stream>>>(xw2, as2, ad2, al, ar, mkey, N);
    k_edgemax<<<gE, 256, 0, stream>>>(ei, al, ar, mkey, E);
    k_denominit<<<gN, 256, 0, stream>>>(al, ar, mkey, denom, N);
    k_edgesum<<<gE, 256, 0, stream>>>(ei, al, ar, mf, denom, E);
    k_selfscatter<<<gN16, 256, 0, stream>>>(xw2, al, ar, mf, denom, out2, N);
    k_edgescatter<<<gE16, 256, 0, stream>>>(ei, xw2, al, ar, mf, denom, out2, E);
    k_elu2<<<gN16, 256, 0, stream>>>(out2, b2v, out, N);

    // ---- pooling + logits (logits live at out + N*64) ----
    hipMemsetAsync(pooled, 0, (NG * 64 + NG) * sizeof(float), stream);
    int waves = (N + 255) / 256;
    k_pool<<<(waves * 64 + 255) / 256, 256, 0, stream>>>(out2, batch, pooled, cnt, N);
    k_logits<<<1, 64, 0, stream>>>(pooled, cnt, fcW, fcb, out + nv);
}

// Round 4
// 1086.870 us; speedup vs baseline: 3.9938x; 3.9938x over previous
//
#include <hip/hip_runtime.h>

#define NEG_SLOPE 0.2f
#define NG 8

__device__ __forceinline__ float lrelu(float x) { return x > 0.f ? x : NEG_SLOPE * x; }
__device__ __forceinline__ float eluf(float x) { return x > 0.f ? x : expm1f(x); }
__device__ __forceinline__ float wave_max(float v) {
    #pragma unroll
    for (int o = 32; o; o >>= 1) v = fmaxf(v, __shfl_xor(v, o));
    return v;
}
__device__ __forceinline__ float wave_sum(float v) {
    #pragma unroll
    for (int o = 32; o; o >>= 1) v += __shfl_xor(v, o);
    return v;
}

// ---------------- CSR build ----------------------------------------------------
__global__ __launch_bounds__(256) void k_hist(const int* __restrict__ ei,
                                              int* __restrict__ deg, int E) {
    int e = blockIdx.x * 256 + threadIdx.x;
    if (e < E) atomicAdd(&deg[ei[E + e]], 1);
}

// single-block Hillis-Steele scan over N elements -> row_ptr (exclusive) + cursor copy
__global__ __launch_bounds__(1024) void k_scan(const int* __restrict__ deg,
                                               int* __restrict__ rp,
                                               int* __restrict__ cur, int N) {
    __shared__ int sm[1024];
    __shared__ int carry;
    int t = threadIdx.x;
    if (t == 0) carry = 0;
    __syncthreads();
    for (int base = 0; base < N; base += 1024) {
        int v = (base + t < N) ? deg[base + t] : 0;
        sm[t] = v;
        __syncthreads();
        int x = v;
        for (int off = 1; off < 1024; off <<= 1) {
            int y = (t >= off) ? sm[t - off] : 0;
            __syncthreads();
            x += y;
            sm[t] = x;
            __syncthreads();
        }
        int excl = x - v + carry;               // reads carry before update below
        if (base + t < N) { rp[base + t] = excl; cur[base + t] = excl; }
        __syncthreads();
        if (t == 1023) carry += x;              // x at t=1023 = chunk total
        __syncthreads();
    }
    if (t == 0) rp[N] = carry;
}

__global__ __launch_bounds__(256) void k_fill(const int* __restrict__ ei,
                                              int* __restrict__ cur,
                                              int* __restrict__ csr, int E) {
    int e = blockIdx.x * 256 + threadIdx.x;
    if (e >= E) return;
    int s = ei[e], d = ei[E + e];
    int pos = atomicAdd(&cur[d], 1);
    csr[pos] = s;
}

// ---------------- GEMM1 per head: xw1h[N,64] = x[N,256] @ W1[:,h*64:h*64+64] ----
__global__ __launch_bounds__(256) void k_gemm1h(const float* __restrict__ x,
                                                const float* __restrict__ W1,
                                                int head, float* __restrict__ xw1h, int N) {
    __shared__ float As[16][256];
    int r0 = blockIdx.x * 16;
    int c = threadIdx.x & 63, rq = threadIdx.x >> 6;
    for (int i = threadIdx.x; i < 1024; i += 256) {
        int r = i >> 6, k4 = (i & 63) << 2;
        float4 v = (r0 + r < N) ? *(const float4*)(x + (size_t)(r0 + r) * 256 + k4)
                                : make_float4(0.f, 0.f, 0.f, 0.f);
        As[r][k4] = v.x; As[r][k4 + 1] = v.y; As[r][k4 + 2] = v.z; As[r][k4 + 3] = v.w;
    }
    __syncthreads();
    float acc[4] = {0.f, 0.f, 0.f, 0.f};
    const float* Wc = W1 + head * 64 + c;
    #pragma unroll 4
    for (int k = 0; k < 256; k++) {
        float w = Wc[(size_t)k * 256];
        #pragma unroll
        for (int t = 0; t < 4; t++) acc[t] += As[rq + 4 * t][k] * w;
    }
    #pragma unroll
    for (int t = 0; t < 4; t++) {
        int r = r0 + rq + 4 * t;
        if (r < N) xw1h[(size_t)r * 64 + c] = acc[t];
    }
}

// ---------------- per-node attention dots --------------------------------------
__global__ __launch_bounds__(256) void k_alar(const float* __restrict__ xw,
                                              const float* __restrict__ a_s,
                                              const float* __restrict__ a_d,
                                              float* __restrict__ al, float* __restrict__ ar,
                                              int N) {
    int n = blockIdx.x * 256 + threadIdx.x;
    if (n >= N) return;
    const float* row = xw + (size_t)n * 64;
    float sl = 0.f, sr = 0.f;
    #pragma unroll 8
    for (int c = 0; c < 64; c++) {
        float v = row[c];
        sl += v * a_s[c];
        sr += v * a_d[c];
    }
    al[n] = sl; ar[n] = sr;
}

// ---------------- fused softmax + aggregate: one wave per dst node --------------
__global__ __launch_bounds__(256) void k_agg(const int* __restrict__ rp,
                                             const int* __restrict__ csr,
                                             const float* __restrict__ al,
                                             const float* __restrict__ ar,
                                             const float* __restrict__ xw,
                                             float* __restrict__ outb, int N) {
    int n = (blockIdx.x * 256 + threadIdx.x) >> 6;
    int lane = threadIdx.x & 63;
    if (n >= N) return;
    int e0 = rp[n], e1 = rp[n + 1];
    float arn = ar[n];
    float se = lrelu(al[n] + arn);              // self-loop score
    // segment max (self + in-edges), lanes strided over edges
    float vmax = se;
    for (int j = e0 + lane; j < e1; j += 64)
        vmax = fmaxf(vmax, lrelu(al[csr[j]] + arn));
    float m = wave_max(vmax);
    // denom
    float ssum = 0.f;
    for (int j = e0 + lane; j < e1; j += 64)
        ssum += expf(lrelu(al[csr[j]] + arn) - m);
    float inv = 1.f / (wave_sum(ssum) + expf(se - m));
    // aggregate: all lanes walk the edge list together (broadcast loads),
    // lane = feature column
    float acc = expf(se - m) * inv * xw[(size_t)n * 64 + lane];
    for (int j = e0; j < e1; j++) {
        int s = csr[j];
        float a = expf(lrelu(al[s] + arn) - m) * inv;
        acc += a * xw[(size_t)s * 64 + lane];
    }
    outb[(size_t)n * 64 + lane] = acc;
}

// ---------------- xw2 (+)= elu(out1h + b1[head]) @ W2[h*64:(h+1)*64, :] ---------
__global__ __launch_bounds__(256) void k_gemm2acc(const float* __restrict__ out1h,
                                                  const float* __restrict__ b1, int head,
                                                  const float* __restrict__ W2,
                                                  float* __restrict__ xw2, int N, int first) {
    __shared__ float Hs[16][64];
    int r0 = blockIdx.x * 16;
    int j = threadIdx.x & 63, rq = threadIdx.x >> 6;
    {
        int r = threadIdx.x >> 4, c4 = (threadIdx.x & 15) << 2;
        float4 v = (r0 + r < N) ? *(const float4*)(out1h + (size_t)(r0 + r) * 64 + c4)
                                : make_float4(0.f, 0.f, 0.f, 0.f);
        Hs[r][c4]     = eluf(v.x + b1[head * 64 + c4]);
        Hs[r][c4 + 1] = eluf(v.y + b1[head * 64 + c4 + 1]);
        Hs[r][c4 + 2] = eluf(v.z + b1[head * 64 + c4 + 2]);
        Hs[r][c4 + 3] = eluf(v.w + b1[head * 64 + c4 + 3]);
    }
    __syncthreads();
    float acc[4] = {0.f, 0.f, 0.f, 0.f};
    const float* Wr = W2 + (size_t)head * 64 * 64 + j;
    #pragma unroll 4
    for (int c = 0; c < 64; c++) {
        float w = Wr[(size_t)c * 64];
        #pragma unroll
        for (int t = 0; t < 4; t++) acc[t] += Hs[rq + 4 * t][c] * w;
    }
    #pragma unroll
    for (int t = 0; t < 4; t++) {
        int r = r0 + rq + 4 * t;
        if (r < N) {
            size_t o = (size_t)r * 64 + j;
            xw2[o] = first ? acc[t] : (xw2[o] + acc[t]);
        }
    }
}

// ---------------- bias + ELU + emit h ------------------------------------------
__global__ __launch_bounds__(256) void k_elu2(float* __restrict__ out2,
                                              const float* __restrict__ b2,
                                              float* __restrict__ hout, int N) {
    int t = blockIdx.x * 256 + threadIdx.x;
    if (t >= N * 16) return;
    int n = t >> 4; int c4 = (t & 15) << 2;
    float4 v = *(float4*)(out2 + (size_t)n * 64 + c4);
    v.x = eluf(v.x + b2[c4 + 0]);
    v.y = eluf(v.y + b2[c4 + 1]);
    v.z = eluf(v.z + b2[c4 + 2]);
    v.w = eluf(v.w + b2[c4 + 3]);
    *(float4*)(out2 + (size_t)n * 64 + c4) = v;
    *(float4*)(hout + (size_t)n * 64 + c4) = v;
}

// ---------------- mean pool (batch sorted) + logits ----------------------------
__global__ __launch_bounds__(256) void k_pool(const float* __restrict__ h2,
                                              const int* __restrict__ batch,
                                              float* __restrict__ pooled,
                                              float* __restrict__ cnt, int N) {
    int wave = (blockIdx.x * 256 + threadIdx.x) >> 6;
    int lane = threadIdx.x & 63;
    int n0 = wave * 256;
    if (n0 >= N) return;
    int n1 = min(n0 + 256, N);
    float acc = 0.f; int cl = 0;
    int curg = batch[n0];
    for (int n = n0; n < n1; n++) {
        int g = batch[n];
        if (g != curg) {
            atomicAdd(&pooled[curg * 64 + lane], acc);
            if (lane == 0) atomicAdd(&cnt[curg], (float)cl);
            acc = 0.f; cl = 0; curg = g;
        }
        acc += h2[(size_t)n * 64 + lane];
        cl++;
    }
    atomicAdd(&pooled[curg * 64 + lane], acc);
    if (lane == 0) atomicAdd(&cnt[curg], (float)cl);
}

__global__ __launch_bounds__(64) void k_logits(const float* __restrict__ pooled,
                                               const float* __restrict__ cnt,
                                               const float* __restrict__ fcW,
                                               const float* __restrict__ fcb,
                                               float* __restrict__ out) {
    int t = threadIdx.x;
    if (t >= NG * 2) return;
    int g = t >> 1, o = t & 1;
    float invc = 1.f / fmaxf(cnt[g], 1.f);
    float s = 0.f;
    for (int c = 0; c < 64; c++)
        s += pooled[g * 64 + c] * invc * fcW[c * 2 + o];
    s += fcb[o];
    out[g * 2 + o] = s;
}

extern "C" void kernel_launch(void* const* d_in, const int* in_sizes, int n_in,
                              void* d_out, int out_size, void* d_ws, size_t ws_size,
                              hipStream_t stream) {
    const float* x     = (const float*)d_in[0];
    const int*   ei    = (const int*)d_in[1];
    const int*   batch = (const int*)d_in[2];
    const float* W1    = (const float*)d_in[3];
    const float* as1   = (const float*)d_in[4];
    const float* ad1   = (const float*)d_in[5];
    const float* b1    = (const float*)d_in[6];
    const float* W2    = (const float*)d_in[7];
    const float* as2   = (const float*)d_in[8];
    const float* ad2   = (const float*)d_in[9];
    const float* b2v   = (const float*)d_in[10];
    const float* fcW   = (const float*)d_in[11];
    const float* fcb   = (const float*)d_in[12];
    float* out = (float*)d_out;

    const int N = in_sizes[2];       // 50000
    const int E = in_sizes[1] / 2;   // 800000
    const size_t nv = (size_t)N * 64;

    // workspace layout: 3*nv + 2N + 520 floats, then int CSR arrays (~42.6 MB total)
    float* ws = (float*)d_ws;
    float* xw1h   = ws;               // nv (reused as out2 in layer 2)
    float* out1h  = ws + nv;          // nv
    float* xw2    = ws + 2 * nv;      // nv
    float* al     = ws + 3 * nv;      // N
    float* ar     = al + N;           // N
    float* pooled = ar + N;           // 512
    float* cnt    = pooled + NG * 64; // 8
    int*   deg    = (int*)(cnt + 8);  // N
    int*   rp     = deg + N;          // N+1
    int*   cur    = rp + N + 1;       // N
    int*   csr    = cur + N;          // E
    float* out2   = xw1h;

    const int gN   = (N + 255) / 256;
    const int gE   = (E + 255) / 256;
    const int gN16 = (N * 16 + 255) / 256;
    const int gW   = (N * 64 + 255) / 256;   // one wave per node
    const int gT   = (N + 15) / 16;

    // ---- CSR build (shared by all 5 aggregation passes) ----
    hipMemsetAsync(deg, 0, (size_t)N * sizeof(int), stream);
    k_hist<<<gE, 256, 0, stream>>>(ei, deg, E);
    k_scan<<<1, 1024, 0, stream>>>(deg, rp, cur, N);
    k_fill<<<gE, 256, 0, stream>>>(ei, cur, csr, E);

    // ---- layer 1, per head; fused elu+GEMM2 accumulation ----
    for (int h = 0; h < 4; h++) {
        k_gemm1h<<<gT, 256, 0, stream>>>(x, W1, h, xw1h, N);
        k_alar<<<gN, 256, 0, stream>>>(xw1h, as1 + h * 64, ad1 + h * 64, al, ar, N);
        k_agg<<<gW, 256, 0, stream>>>(rp, csr, al, ar, xw1h, out1h, N);
        k_gemm2acc<<<gT, 256, 0, stream>>>(out1h, b1, h, W2, xw2, N, h == 0);
    }

    // ---- layer 2 (single head) ----
    k_alar<<<gN, 256, 0, stream>>>(xw2, as2, ad2, al, ar, N);
    k_agg<<<gW, 256, 0, stream>>>(rp, csr, al, ar, xw2, out2, N);
    k_elu2<<<gN16, 256, 0, stream>>>(out2, b2v, out, N);

    // ---- pooling + logits ----
    hipMemsetAsync(pooled, 0, (NG * 64 + NG) * sizeof(float), stream);
    int waves = (N + 255) / 256;
    k_pool<<<(waves * 64 + 255) / 256, 256, 0, stream>>>(out2, batch, pooled, cnt, N);
    k_logits<<<1, 64, 0, stream>>>(pooled, cnt, fcW, fcb, out + nv);
}

// Round 5
// 942.280 us; speedup vs baseline: 4.6067x; 1.1534x over previous
//
#include <hip/hip_runtime.h>

#define NEG_SLOPE 0.2f
#define NG 8

__device__ __forceinline__ float lrelu(float x) { return x > 0.f ? x : NEG_SLOPE * x; }
__device__ __forceinline__ float eluf(float x) { return x > 0.f ? x : expm1f(x); }
__device__ __forceinline__ unsigned enc(float x) {
    unsigned u = __float_as_uint(x);
    return (u & 0x80000000u) ? ~u : (u | 0x80000000u);
}
__device__ __forceinline__ float dec(unsigned k) {
    return (k & 0x80000000u) ? __uint_as_float(k & 0x7fffffffu) : __uint_as_float(~k);
}
__device__ __forceinline__ float wave_sum(float v) {
    #pragma unroll
    for (int o = 32; o; o >>= 1) v += __shfl_xor(v, o);
    return v;
}

// ---------------- CSR build ----------------------------------------------------
__global__ __launch_bounds__(256) void k_hist(const int* __restrict__ ei,
                                              int* __restrict__ deg, int E) {
    int e = blockIdx.x * 256 + threadIdx.x;
    if (e < E) atomicAdd(&deg[ei[E + e]], 1);
}

__global__ __launch_bounds__(1024) void k_scan(const int* __restrict__ deg,
                                               int* __restrict__ rp,
                                               int* __restrict__ cur, int N) {
    __shared__ int sm[1024];
    __shared__ int carry;
    int t = threadIdx.x;
    if (t == 0) carry = 0;
    __syncthreads();
    for (int base = 0; base < N; base += 1024) {
        int v = (base + t < N) ? deg[base + t] : 0;
        sm[t] = v;
        __syncthreads();
        int x = v;
        for (int off = 1; off < 1024; off <<= 1) {
            int y = (t >= off) ? sm[t - off] : 0;
            __syncthreads();
            x += y;
            sm[t] = x;
            __syncthreads();
        }
        int excl = x - v + carry;
        if (base + t < N) { rp[base + t] = excl; cur[base + t] = excl; }
        __syncthreads();
        if (t == 1023) carry += x;
        __syncthreads();
    }
    if (t == 0) rp[N] = carry;
}

__global__ __launch_bounds__(256) void k_fill(const int* __restrict__ ei,
                                              int* __restrict__ cur,
                                              int* __restrict__ csr, int E) {
    int e = blockIdx.x * 256 + threadIdx.x;
    if (e >= E) return;
    int s = ei[e], d = ei[E + e];
    int pos = atomicAdd(&cur[d], 1);
    csr[pos] = s;
}

// ---------------- GEMM1: xw1[N,256] = x[N,256] @ W1[256,256] --------------------
__global__ __launch_bounds__(256) void k_gemm1(const float* __restrict__ x,
                                               const float* __restrict__ W1,
                                               float* __restrict__ xw1, int N) {
    __shared__ float As[16][256];
    int r0 = blockIdx.x * 16;
    int lane = threadIdx.x & 63, rq = threadIdx.x >> 6;
    int c4 = lane << 2;
    for (int i = threadIdx.x; i < 1024; i += 256) {
        int r = i >> 6, k4 = (i & 63) << 2;
        float4 v = (r0 + r < N) ? *(const float4*)(x + (size_t)(r0 + r) * 256 + k4)
                                : make_float4(0.f, 0.f, 0.f, 0.f);
        As[r][k4] = v.x; As[r][k4 + 1] = v.y; As[r][k4 + 2] = v.z; As[r][k4 + 3] = v.w;
    }
    __syncthreads();
    float4 acc[4];
    #pragma unroll
    for (int t = 0; t < 4; t++) acc[t] = make_float4(0.f, 0.f, 0.f, 0.f);
    for (int k4 = 0; k4 < 256; k4 += 4) {
        float4 w0 = *(const float4*)(W1 + (size_t)(k4 + 0) * 256 + c4);
        float4 w1 = *(const float4*)(W1 + (size_t)(k4 + 1) * 256 + c4);
        float4 w2 = *(const float4*)(W1 + (size_t)(k4 + 2) * 256 + c4);
        float4 w3 = *(const float4*)(W1 + (size_t)(k4 + 3) * 256 + c4);
        #pragma unroll
        for (int t = 0; t < 4; t++) {
            int r = rq + 4 * t;
            float4 a = *(const float4*)(&As[r][k4]);   // wave-uniform broadcast
            acc[t].x += a.x * w0.x + a.y * w1.x + a.z * w2.x + a.w * w3.x;
            acc[t].y += a.x * w0.y + a.y * w1.y + a.z * w2.y + a.w * w3.y;
            acc[t].z += a.x * w0.z + a.y * w1.z + a.z * w2.z + a.w * w3.z;
            acc[t].w += a.x * w0.w + a.y * w1.w + a.z * w2.w + a.w * w3.w;
        }
    }
    #pragma unroll
    for (int t = 0; t < 4; t++) {
        int r = r0 + rq + 4 * t;
        if (r < N) *(float4*)(xw1 + (size_t)r * 256 + c4) = acc[t];
    }
}

// ---------------- al/ar for all 4 heads, one wave per node ----------------------
__global__ __launch_bounds__(256) void k_alar4(const float* __restrict__ xw1,
                                               const float* __restrict__ a_s,
                                               const float* __restrict__ a_d,
                                               float* __restrict__ al4, float* __restrict__ ar4,
                                               unsigned* __restrict__ m4key, int N) {
    int n = (blockIdx.x * 256 + threadIdx.x) >> 6;
    int lane = threadIdx.x & 63;
    if (n >= N) return;
    float4 v = *(const float4*)(xw1 + (size_t)n * 256 + lane * 4);
    int h = lane >> 4, kk = (lane * 4) & 63;
    float4 s4 = *(const float4*)(a_s + h * 64 + kk);
    float4 d4 = *(const float4*)(a_d + h * 64 + kk);
    float sl = v.x * s4.x + v.y * s4.y + v.z * s4.z + v.w * s4.w;
    float sr = v.x * d4.x + v.y * d4.y + v.z * d4.z + v.w * d4.w;
    #pragma unroll
    for (int o = 1; o < 16; o <<= 1) { sl += __shfl_xor(sl, o); sr += __shfl_xor(sr, o); }
    if ((lane & 15) == 0) {
        al4[(size_t)n * 4 + h] = sl;
        ar4[(size_t)n * 4 + h] = sr;
        m4key[(size_t)n * 4 + h] = enc(lrelu(sl + sr));   // self-loop seed
    }
}

// ---------------- edge-parallel segment max, 4 heads ----------------------------
__global__ __launch_bounds__(256) void k_edgemax4(const int* __restrict__ ei,
                                                  const float* __restrict__ al4,
                                                  const float* __restrict__ ar4,
                                                  unsigned* __restrict__ m4key, int E) {
    int e = blockIdx.x * 256 + threadIdx.x;
    if (e >= E) return;
    int s = ei[e], d = ei[E + e];
    float4 a = *(const float4*)(al4 + (size_t)s * 4);
    float4 b = *(const float4*)(ar4 + (size_t)d * 4);
    atomicMax(&m4key[(size_t)d * 4 + 0], enc(lrelu(a.x + b.x)));
    atomicMax(&m4key[(size_t)d * 4 + 1], enc(lrelu(a.y + b.y)));
    atomicMax(&m4key[(size_t)d * 4 + 2], enc(lrelu(a.z + b.z)));
    atomicMax(&m4key[(size_t)d * 4 + 3], enc(lrelu(a.w + b.w)));
}

// ---------------- per-edge weights + denom, 4 heads (wave per node) -------------
__global__ __launch_bounds__(256) void k_w4(const int* __restrict__ rp,
                                            const int* __restrict__ csr,
                                            const float* __restrict__ al4,
                                            const float* __restrict__ ar4,
                                            const unsigned* __restrict__ m4key,
                                            float* __restrict__ w4,
                                            float* __restrict__ denom4,
                                            float* __restrict__ wself4, int N) {
    int n = (blockIdx.x * 256 + threadIdx.x) >> 6;
    int lane = threadIdx.x & 63;
    if (n >= N) return;
    int e0 = rp[n], e1 = rp[n + 1];
    uint4 mk = *(const uint4*)(m4key + (size_t)n * 4);
    float4 m4 = make_float4(dec(mk.x), dec(mk.y), dec(mk.z), dec(mk.w));
    float4 arn = *(const float4*)(ar4 + (size_t)n * 4);
    float4 aln = *(const float4*)(al4 + (size_t)n * 4);
    float4 ws4;
    ws4.x = expf(lrelu(aln.x + arn.x) - m4.x);
    ws4.y = expf(lrelu(aln.y + arn.y) - m4.y);
    ws4.z = expf(lrelu(aln.z + arn.z) - m4.z);
    ws4.w = expf(lrelu(aln.w + arn.w) - m4.w);
    float sx = 0.f, sy = 0.f, sz = 0.f, sw = 0.f;
    for (int j = e0 + lane; j < e1; j += 64) {
        int s = csr[j];
        float4 a = *(const float4*)(al4 + (size_t)s * 4);
        float4 w;
        w.x = expf(lrelu(a.x + arn.x) - m4.x);
        w.y = expf(lrelu(a.y + arn.y) - m4.y);
        w.z = expf(lrelu(a.z + arn.z) - m4.z);
        w.w = expf(lrelu(a.w + arn.w) - m4.w);
        *(float4*)(w4 + (size_t)j * 4) = w;
        sx += w.x; sy += w.y; sz += w.z; sw += w.w;
    }
    sx = wave_sum(sx); sy = wave_sum(sy); sz = wave_sum(sz); sw = wave_sum(sw);
    if (lane == 0) {
        *(float4*)(denom4 + (size_t)n * 4) = make_float4(sx + ws4.x, sy + ws4.y, sz + ws4.z, sw + ws4.w);
        *(float4*)(wself4 + (size_t)n * 4) = ws4;
    }
}

// ---------------- aggregate 4 heads + fused ELU/b1 + GEMM2 + alar2 --------------
__global__ __launch_bounds__(256) void k_agg4(const int* __restrict__ rp,
                                              const int* __restrict__ csr,
                                              const float* __restrict__ w4,
                                              const float* __restrict__ denom4,
                                              const float* __restrict__ wself4,
                                              const float* __restrict__ xw1,
                                              const float* __restrict__ b1,
                                              const float* __restrict__ W2,
                                              const float* __restrict__ as2,
                                              const float* __restrict__ ad2,
                                              float* __restrict__ xw2,
                                              float* __restrict__ al2, float* __restrict__ ar2,
                                              unsigned* __restrict__ m2key, int N) {
    __shared__ float hs[4][256];
    int wIdx = threadIdx.x >> 6;
    int n = (blockIdx.x * 256 + threadIdx.x) >> 6;
    int lane = threadIdx.x & 63;
    bool act = n < N;
    if (act) {
        int e0 = rp[n], e1 = rp[n + 1];
        float4 dn = *(const float4*)(denom4 + (size_t)n * 4);
        float4 wsf = *(const float4*)(wself4 + (size_t)n * 4);
        float4 inv = make_float4(1.f / dn.x, 1.f / dn.y, 1.f / dn.z, 1.f / dn.w);
        const float* xr = xw1 + (size_t)n * 256;
        float a0 = wsf.x * xr[lane];
        float a1 = wsf.y * xr[64 + lane];
        float a2 = wsf.z * xr[128 + lane];
        float a3 = wsf.w * xr[192 + lane];
        for (int j = e0; j < e1; j++) {
            int s = csr[j];                                   // broadcast
            float4 w = *(const float4*)(w4 + (size_t)j * 4);  // broadcast
            const float* sr_ = xw1 + (size_t)s * 256;
            a0 += w.x * sr_[lane];
            a1 += w.y * sr_[64 + lane];
            a2 += w.z * sr_[128 + lane];
            a3 += w.w * sr_[192 + lane];
        }
        hs[wIdx][lane]       = eluf(a0 * inv.x + b1[lane]);
        hs[wIdx][64 + lane]  = eluf(a1 * inv.y + b1[64 + lane]);
        hs[wIdx][128 + lane] = eluf(a2 * inv.z + b1[128 + lane]);
        hs[wIdx][192 + lane] = eluf(a3 * inv.w + b1[192 + lane]);
    }
    __syncthreads();
    if (act) {
        // xw2[n][lane] = elu_row . W2[:,lane]
        float acc2 = 0.f;
        #pragma unroll 4
        for (int k = 0; k < 256; k++)
            acc2 += hs[wIdx][k] * W2[(size_t)k * 64 + lane];
        xw2[(size_t)n * 64 + lane] = acc2;
        float sl = wave_sum(acc2 * as2[lane]);
        float sr = wave_sum(acc2 * ad2[lane]);
        if (lane == 0) {
            al2[n] = sl; ar2[n] = sr;
            m2key[n] = enc(lrelu(sl + sr));   // self-loop seed, layer 2
        }
    }
}

// ---------------- layer-2 edge max / weights / aggregate ------------------------
__global__ __launch_bounds__(256) void k_edgemax2(const int* __restrict__ ei,
                                                  const float* __restrict__ al,
                                                  const float* __restrict__ ar,
                                                  unsigned* __restrict__ mkey, int E) {
    int e = blockIdx.x * 256 + threadIdx.x;
    if (e >= E) return;
    int s = ei[e], d = ei[E + e];
    atomicMax(&mkey[d], enc(lrelu(al[s] + ar[d])));
}

__global__ __launch_bounds__(256) void k_w2(const int* __restrict__ rp,
                                            const int* __restrict__ csr,
                                            const float* __restrict__ al,
                                            const float* __restrict__ ar,
                                            const unsigned* __restrict__ mkey,
                                            float* __restrict__ w2,
                                            float* __restrict__ denom2,
                                            float* __restrict__ wself2, int N) {
    int n = (blockIdx.x * 256 + threadIdx.x) >> 6;
    int lane = threadIdx.x & 63;
    if (n >= N) return;
    int e0 = rp[n], e1 = rp[n + 1];
    float m = dec(mkey[n]);
    float arn = ar[n];
    float selfw = expf(lrelu(al[n] + arn) - m);
    float ssum = 0.f;
    for (int j = e0 + lane; j < e1; j += 64) {
        float w = expf(lrelu(al[csr[j]] + arn) - m);
        w2[j] = w;
        ssum += w;
    }
    ssum = wave_sum(ssum);
    if (lane == 0) { denom2[n] = ssum + selfw; wself2[n] = selfw; }
}

__global__ __launch_bounds__(256) void k_agg2(const int* __restrict__ rp,
                                              const int* __restrict__ csr,
                                              const float* __restrict__ w2,
                                              const float* __restrict__ denom2,
                                              const float* __restrict__ wself2,
                                              const float* __restrict__ xw2,
                                              const float* __restrict__ b2,
                                              float* __restrict__ hout, int N) {
    int n = (blockIdx.x * 256 + threadIdx.x) >> 6;
    int lane = threadIdx.x & 63;
    if (n >= N) return;
    int e0 = rp[n], e1 = rp[n + 1];
    float inv = 1.f / denom2[n];
    float acc = wself2[n] * xw2[(size_t)n * 64 + lane];
    for (int j = e0; j < e1; j++) {
        int s = csr[j];
        float w = w2[j];
        acc += w * xw2[(size_t)s * 64 + lane];
    }
    hout[(size_t)n * 64 + lane] = eluf(acc * inv + b2[lane]);
}

// ---------------- mean pool (batch sorted, 32 nodes/wave) + logits --------------
__global__ __launch_bounds__(256) void k_pool(const float* __restrict__ h2,
                                              const int* __restrict__ batch,
                                              float* __restrict__ pooled,
                                              float* __restrict__ cnt, int N) {
    int wave = (blockIdx.x * 256 + threadIdx.x) >> 6;
    int lane = threadIdx.x & 63;
    int n0 = wave * 32;
    if (n0 >= N) return;
    int n1 = min(n0 + 32, N);
    float acc = 0.f; int cl = 0;
    int curg = batch[n0];
    for (int n = n0; n < n1; n++) {
        int g = batch[n];
        if (g != curg) {
            atomicAdd(&pooled[curg * 64 + lane], acc);
            if (lane == 0) atomicAdd(&cnt[curg], (float)cl);
            acc = 0.f; cl = 0; curg = g;
        }
        acc += h2[(size_t)n * 64 + lane];
        cl++;
    }
    atomicAdd(&pooled[curg * 64 + lane], acc);
    if (lane == 0) atomicAdd(&cnt[curg], (float)cl);
}

__global__ __launch_bounds__(64) void k_logits(const float* __restrict__ pooled,
                                               const float* __restrict__ cnt,
                                               const float* __restrict__ fcW,
                                               const float* __restrict__ fcb,
                                               float* __restrict__ out) {
    int t = threadIdx.x;
    if (t >= NG * 2) return;
    int g = t >> 1, o = t & 1;
    float invc = 1.f / fmaxf(cnt[g], 1.f);
    float s = 0.f;
    for (int c = 0; c < 64; c++)
        s += pooled[g * 64 + c] * invc * fcW[c * 2 + o];
    s += fcb[o];
    out[g * 2 + o] = s;
}

extern "C" void kernel_launch(void* const* d_in, const int* in_sizes, int n_in,
                              void* d_out, int out_size, void* d_ws, size_t ws_size,
                              hipStream_t stream) {
    const float* x     = (const float*)d_in[0];
    const int*   ei    = (const int*)d_in[1];
    const int*   batch = (const int*)d_in[2];
    const float* W1    = (const float*)d_in[3];
    const float* as1   = (const float*)d_in[4];
    const float* ad1   = (const float*)d_in[5];
    const float* b1    = (const float*)d_in[6];
    const float* W2    = (const float*)d_in[7];
    const float* as2   = (const float*)d_in[8];
    const float* ad2   = (const float*)d_in[9];
    const float* b2v   = (const float*)d_in[10];
    const float* fcW   = (const float*)d_in[11];
    const float* fcb   = (const float*)d_in[12];
    float* out = (float*)d_out;

    const int N = in_sizes[2];       // 50000
    const int E = in_sizes[1] / 2;   // 800000
    const size_t nv  = (size_t)N * 64;
    const size_t nv4 = (size_t)N * 256;

    // workspace layout (floats); ~86 MB total
    float*    ws     = (float*)d_ws;
    float*    xw1    = ws;                       // nv4
    float*    xw2    = xw1 + nv4;                // nv
    float*    w4     = xw2 + nv;                 // E*4 (w2 aliases)
    float*    al4    = w4 + (size_t)E * 4;       // N*4
    float*    ar4    = al4 + (size_t)N * 4;      // N*4
    unsigned* m4key  = (unsigned*)(ar4 + (size_t)N * 4);  // N*4
    float*    denom4 = (float*)(m4key + (size_t)N * 4);   // N*4
    float*    wself4 = denom4 + (size_t)N * 4;   // N*4
    float*    al2    = wself4 + (size_t)N * 4;   // N
    float*    ar2    = al2 + N;                  // N
    unsigned* m2key  = (unsigned*)(ar2 + N);     // N
    float*    denom2 = (float*)(m2key + N);      // N
    float*    wself2 = denom2 + N;               // N
    float*    pooled = wself2 + N;               // 512
    float*    cnt    = pooled + NG * 64;         // 8
    int*      deg    = (int*)(cnt + 8);          // N
    int*      rp     = deg + N;                  // N+1
    int*      cur    = rp + N + 1;               // N
    int*      csr    = cur + N;                  // E
    float*    w2     = w4;                       // alias (w4 dead after k_agg4)

    const int gE  = (E + 255) / 256;
    const int gW  = ((int)((nv + 255) / 256));           // one wave per node
    const int gB4 = (N + 3) / 4;                         // 4 nodes per block
    const int gG1 = (N + 15) / 16;
    const int pw  = (N + 31) / 32;
    const int gP  = (pw * 64 + 255) / 256;

    // ---- CSR build ----
    hipMemsetAsync(deg, 0, (size_t)N * sizeof(int), stream);
    k_hist<<<gE, 256, 0, stream>>>(ei, deg, E);
    k_scan<<<1, 1024, 0, stream>>>(deg, rp, cur, N);
    k_fill<<<gE, 256, 0, stream>>>(ei, cur, csr, E);

    // ---- layer 1 (all heads fused) ----
    k_gemm1<<<gG1, 256, 0, stream>>>(x, W1, xw1, N);
    k_alar4<<<gW, 256, 0, stream>>>(xw1, as1, ad1, al4, ar4, m4key, N);
    k_edgemax4<<<gE, 256, 0, stream>>>(ei, al4, ar4, m4key, E);
    k_w4<<<gW, 256, 0, stream>>>(rp, csr, al4, ar4, m4key, w4, denom4, wself4, N);
    k_agg4<<<gB4, 256, 0, stream>>>(rp, csr, w4, denom4, wself4, xw1, b1, W2,
                                    as2, ad2, xw2, al2, ar2, m2key, N);

    // ---- layer 2 ----
    k_edgemax2<<<gE, 256, 0, stream>>>(ei, al2, ar2, m2key, E);
    k_w2<<<gW, 256, 0, stream>>>(rp, csr, al2, ar2, m2key, w2, denom2, wself2, N);
    k_agg2<<<gW, 256, 0, stream>>>(rp, csr, w2, denom2, wself2, xw2, b2v, out, N);

    // ---- pooling + logits ----
    hipMemsetAsync(pooled, 0, (NG * 64 + NG) * sizeof(float), stream);
    k_pool<<<gP, 256, 0, stream>>>(out, batch, pooled, cnt, N);
    k_logits<<<1, 64, 0, stream>>>(pooled, cnt, fcW, fcb, out + nv);
}

// Round 7
// 599.891 us; speedup vs baseline: 7.2359x; 1.5708x over previous
//
#include <hip/hip_runtime.h>

#define NEG_SLOPE 0.2f
#define NG 8

__device__ __forceinline__ float lrelu(float x) { return x > 0.f ? x : NEG_SLOPE * x; }
__device__ __forceinline__ float eluf(float x) { return x > 0.f ? x : expm1f(x); }
__device__ __forceinline__ float wave_sum(float v) {
    #pragma unroll
    for (int o = 32; o; o >>= 1) v += __shfl_xor(v, o);
    return v;
}

// ---------------- CSR build ----------------------------------------------------
__global__ __launch_bounds__(256) void k_hist(const int* __restrict__ ei,
                                              int* __restrict__ deg, int E) {
    int e = blockIdx.x * 256 + threadIdx.x;
    if (e < E) atomicAdd(&deg[ei[E + e]], 1);
}

// phase A: per-block (1024 elems) totals
__global__ __launch_bounds__(256) void k_scanA(const int* __restrict__ deg,
                                               int* __restrict__ bsum, int N) {
    __shared__ int wsums[4];
    int b = blockIdx.x, t = threadIdx.x;
    int base = b * 1024 + t * 4;
    int s = 0;
    #pragma unroll
    for (int k = 0; k < 4; k++) { int i = base + k; if (i < N) s += deg[i]; }
    // integer wave reduce
    #pragma unroll
    for (int o = 32; o; o >>= 1) s += __shfl_xor(s, o);
    if ((t & 63) == 0) wsums[t >> 6] = s;
    __syncthreads();
    if (t == 0) bsum[b] = wsums[0] + wsums[1] + wsums[2] + wsums[3];
}

// phase B: scan block totals (SB <= 64), write exclusive offsets + grand total
__global__ __launch_bounds__(64) void k_scanB(const int* __restrict__ bsum,
                                              int* __restrict__ boff,
                                              int* __restrict__ rpN, int SB) {
    int lane = threadIdx.x;
    int own = (lane < SB) ? bsum[lane] : 0;
    int v = own;
    #pragma unroll
    for (int o = 1; o < 64; o <<= 1) { int y = __shfl_up(v, o); if (lane >= o) v += y; }
    if (lane < SB) boff[lane] = v - own;
    if (lane == 63) *rpN = v;
}

// phase C: full exclusive scan with block offset -> rp + cur
__global__ __launch_bounds__(256) void k_scanC(const int* __restrict__ deg,
                                               const int* __restrict__ boff,
                                               int* __restrict__ rp,
                                               int* __restrict__ cur, int N) {
    __shared__ int wtot[4];
    int b = blockIdx.x, t = threadIdx.x;
    int wid = t >> 6, lane = t & 63;
    int base = b * 1024 + t * 4;
    int d[4];
    #pragma unroll
    for (int k = 0; k < 4; k++) d[k] = (base + k < N) ? deg[base + k] : 0;
    int tsum = d[0] + d[1] + d[2] + d[3];
    int v = tsum;
    #pragma unroll
    for (int o = 1; o < 64; o <<= 1) { int y = __shfl_up(v, o); if (lane >= o) v += y; }
    if (lane == 63) wtot[wid] = v;
    __syncthreads();
    int wbase = 0;
    for (int k = 0; k < wid; k++) wbase += wtot[k];
    int run = boff[b] + wbase + v - tsum;
    #pragma unroll
    for (int k = 0; k < 4; k++) {
        if (base + k < N) { rp[base + k] = run; cur[base + k] = run; }
        run += d[k];
    }
}

__global__ __launch_bounds__(256) void k_fill(const int* __restrict__ ei,
                                              int* __restrict__ cur,
                                              int* __restrict__ csr, int E) {
    int e = blockIdx.x * 256 + threadIdx.x;
    if (e >= E) return;
    int s = ei[e], d = ei[E + e];
    int pos = atomicAdd(&cur[d], 1);
    csr[pos] = s;
}

// ------- GEMM1: xw1 = x @ W1, fused per-head al/ar epilogue ---------------------
__global__ __launch_bounds__(256) void k_gemm1(const float* __restrict__ x,
                                               const float* __restrict__ W1,
                                               const float* __restrict__ a_s,
                                               const float* __restrict__ a_d,
                                               float* __restrict__ xw1,
                                               float* __restrict__ al4,
                                               float* __restrict__ ar4, int N) {
    __shared__ float As[16][256];
    int r0 = blockIdx.x * 16;
    int lane = threadIdx.x & 63, rq = threadIdx.x >> 6;
    int c4 = lane << 2;
    for (int i = threadIdx.x; i < 1024; i += 256) {
        int r = i >> 6, k4 = (i & 63) << 2;
        float4 v = (r0 + r < N) ? *(const float4*)(x + (size_t)(r0 + r) * 256 + k4)
                                : make_float4(0.f, 0.f, 0.f, 0.f);
        As[r][k4] = v.x; As[r][k4 + 1] = v.y; As[r][k4 + 2] = v.z; As[r][k4 + 3] = v.w;
    }
    __syncthreads();
    float4 acc[4];
    #pragma unroll
    for (int t = 0; t < 4; t++) acc[t] = make_float4(0.f, 0.f, 0.f, 0.f);
    for (int k4 = 0; k4 < 256; k4 += 4) {
        float4 w0 = *(const float4*)(W1 + (size_t)(k4 + 0) * 256 + c4);
        float4 w1 = *(const float4*)(W1 + (size_t)(k4 + 1) * 256 + c4);
        float4 w2 = *(const float4*)(W1 + (size_t)(k4 + 2) * 256 + c4);
        float4 w3 = *(const float4*)(W1 + (size_t)(k4 + 3) * 256 + c4);
        #pragma unroll
        for (int t = 0; t < 4; t++) {
            float4 a = *(const float4*)(&As[rq + 4 * t][k4]);
            acc[t].x += a.x * w0.x + a.y * w1.x + a.z * w2.x + a.w * w3.x;
            acc[t].y += a.x * w0.y + a.y * w1.y + a.z * w2.y + a.w * w3.y;
            acc[t].z += a.x * w0.z + a.y * w1.z + a.z * w2.z + a.w * w3.z;
            acc[t].w += a.x * w0.w + a.y * w1.w + a.z * w2.w + a.w * w3.w;
        }
    }
    #pragma unroll
    for (int t = 0; t < 4; t++) {
        int r = r0 + rq + 4 * t;
        if (r < N) *(float4*)(xw1 + (size_t)r * 256 + c4) = acc[t];
    }
    // fused al/ar: head h = lane>>4, within-head cols kk..kk+3
    int h = lane >> 4, kk = c4 & 63;
    float4 s4 = *(const float4*)(a_s + h * 64 + kk);
    float4 d4 = *(const float4*)(a_d + h * 64 + kk);
    #pragma unroll
    for (int t = 0; t < 4; t++) {
        float sl = acc[t].x * s4.x + acc[t].y * s4.y + acc[t].z * s4.z + acc[t].w * s4.w;
        float sr = acc[t].x * d4.x + acc[t].y * d4.y + acc[t].z * d4.z + acc[t].w * d4.w;
        #pragma unroll
        for (int o = 1; o < 16; o <<= 1) { sl += __shfl_xor(sl, o); sr += __shfl_xor(sr, o); }
        int r = r0 + rq + 4 * t;
        if ((lane & 15) == 0 && r < N) {
            al4[(size_t)r * 4 + h] = sl;
            ar4[(size_t)r * 4 + h] = sr;
        }
    }
}

__device__ __forceinline__ float4 wexp4(float4 a, float4 arn) {
    float4 w;
    w.x = __expf(lrelu(a.x + arn.x));
    w.y = __expf(lrelu(a.y + arn.y));
    w.z = __expf(lrelu(a.z + arn.z));
    w.w = __expf(lrelu(a.w + arn.w));
    return w;
}

// ------- layer-1 aggregate (4 heads) + ELU/b1 + GEMM2 + alar2, all fused --------
__global__ __launch_bounds__(256) void k_agg4(const int* __restrict__ rp,
                                              const int* __restrict__ csr,
                                              const float* __restrict__ al4,
                                              const float* __restrict__ ar4,
                                              const float* __restrict__ xw1,
                                              const float* __restrict__ b1,
                                              const float* __restrict__ W2,
                                              const float* __restrict__ as2,
                                              const float* __restrict__ ad2,
                                              float* __restrict__ xw2,
                                              float* __restrict__ al2,
                                              float* __restrict__ ar2, int N) {
    __shared__ float hs[4][256];
    int wIdx = threadIdx.x >> 6;
    int n = (blockIdx.x * 256 + threadIdx.x) >> 6;
    int lane = threadIdx.x & 63;
    bool act = n < N;
    if (act) {
        int e0 = rp[n], e1 = rp[n + 1];
        float4 arn = *(const float4*)(ar4 + (size_t)n * 4);
        float4 aln = *(const float4*)(al4 + (size_t)n * 4);
        float4 wsf = wexp4(aln, arn);           // self-loop weight
        const float* xr = xw1 + (size_t)n * 256;
        float a0 = wsf.x * xr[lane];
        float a1 = wsf.y * xr[64 + lane];
        float a2 = wsf.z * xr[128 + lane];
        float a3 = wsf.w * xr[192 + lane];
        float wx = wsf.x, wy = wsf.y, wz = wsf.z, ww = wsf.w;
        int j = e0;
        for (; j + 4 <= e1; j += 4) {
            int s0 = csr[j], s1 = csr[j + 1], s2 = csr[j + 2], s3 = csr[j + 3];
            float4 A0 = *(const float4*)(al4 + (size_t)s0 * 4);
            float4 A1 = *(const float4*)(al4 + (size_t)s1 * 4);
            float4 A2 = *(const float4*)(al4 + (size_t)s2 * 4);
            float4 A3 = *(const float4*)(al4 + (size_t)s3 * 4);
            const float* r0_ = xw1 + (size_t)s0 * 256;
            const float* r1_ = xw1 + (size_t)s1 * 256;
            const float* r2_ = xw1 + (size_t)s2 * 256;
            const float* r3_ = xw1 + (size_t)s3 * 256;
            float v00 = r0_[lane], v01 = r0_[64 + lane], v02 = r0_[128 + lane], v03 = r0_[192 + lane];
            float v10 = r1_[lane], v11 = r1_[64 + lane], v12 = r1_[128 + lane], v13 = r1_[192 + lane];
            float v20 = r2_[lane], v21 = r2_[64 + lane], v22 = r2_[128 + lane], v23 = r2_[192 + lane];
            float v30 = r3_[lane], v31 = r3_[64 + lane], v32 = r3_[128 + lane], v33 = r3_[192 + lane];
            float4 w0 = wexp4(A0, arn), w1 = wexp4(A1, arn), w2 = wexp4(A2, arn), w3 = wexp4(A3, arn);
            wx += w0.x + w1.x + w2.x + w3.x;
            wy += w0.y + w1.y + w2.y + w3.y;
            wz += w0.z + w1.z + w2.z + w3.z;
            ww += w0.w + w1.w + w2.w + w3.w;
            a0 += w0.x * v00 + w1.x * v10 + w2.x * v20 + w3.x * v30;
            a1 += w0.y * v01 + w1.y * v11 + w2.y * v21 + w3.y * v31;
            a2 += w0.z * v02 + w1.z * v12 + w2.z * v22 + w3.z * v32;
            a3 += w0.w * v03 + w1.w * v13 + w2.w * v23 + w3.w * v33;
        }
        for (; j < e1; j++) {
            int s = csr[j];
            float4 A = *(const float4*)(al4 + (size_t)s * 4);
            const float* r_ = xw1 + (size_t)s * 256;
            float4 w = wexp4(A, arn);
            wx += w.x; wy += w.y; wz += w.z; ww += w.w;
            a0 += w.x * r_[lane];
            a1 += w.y * r_[64 + lane];
            a2 += w.z * r_[128 + lane];
            a3 += w.w * r_[192 + lane];
        }
        hs[wIdx][lane]       = eluf(a0 / wx + b1[lane]);
        hs[wIdx][64 + lane]  = eluf(a1 / wy + b1[64 + lane]);
        hs[wIdx][128 + lane] = eluf(a2 / wz + b1[128 + lane]);
        hs[wIdx][192 + lane] = eluf(a3 / ww + b1[192 + lane]);
    }
    __syncthreads();
    if (act) {
        float acc2 = 0.f;
        #pragma unroll 4
        for (int k = 0; k < 256; k++)
            acc2 += hs[wIdx][k] * W2[(size_t)k * 64 + lane];
        xw2[(size_t)n * 64 + lane] = acc2;
        float sl = wave_sum(acc2 * as2[lane]);
        float sr = wave_sum(acc2 * ad2[lane]);
        if (lane == 0) { al2[n] = sl; ar2[n] = sr; }
    }
}

// ------- layer-2 aggregate + ELU, writes h straight to d_out --------------------
__global__ __launch_bounds__(256) void k_agg2(const int* __restrict__ rp,
                                              const int* __restrict__ csr,
                                              const float* __restrict__ al2,
                                              const float* __restrict__ ar2,
                                              const float* __restrict__ xw2,
                                              const float* __restrict__ b2,
                                              float* __restrict__ hout, int N) {
    int n = (blockIdx.x * 256 + threadIdx.x) >> 6;
    int lane = threadIdx.x & 63;
    if (n >= N) return;
    int e0 = rp[n], e1 = rp[n + 1];
    float arn = ar2[n];
    float wself = __expf(lrelu(al2[n] + arn));
    float acc = wself * xw2[(size_t)n * 64 + lane];
    float wsum = wself;
    int j = e0;
    for (; j + 4 <= e1; j += 4) {
        int s0 = csr[j], s1 = csr[j + 1], s2 = csr[j + 2], s3 = csr[j + 3];
        float A0 = al2[s0], A1 = al2[s1], A2 = al2[s2], A3 = al2[s3];
        float v0 = xw2[(size_t)s0 * 64 + lane];
        float v1 = xw2[(size_t)s1 * 64 + lane];
        float v2 = xw2[(size_t)s2 * 64 + lane];
        float v3 = xw2[(size_t)s3 * 64 + lane];
        float w0 = __expf(lrelu(A0 + arn));
        float w1 = __expf(lrelu(A1 + arn));
        float w2 = __expf(lrelu(A2 + arn));
        float w3 = __expf(lrelu(A3 + arn));
        wsum += w0 + w1 + w2 + w3;
        acc += w0 * v0 + w1 * v1 + w2 * v2 + w3 * v3;
    }
    for (; j < e1; j++) {
        int s = csr[j];
        float w = __expf(lrelu(al2[s] + arn));
        wsum += w;
        acc += w * xw2[(size_t)s * 64 + lane];
    }
    hout[(size_t)n * 64 + lane] = eluf(acc / wsum + b2[lane]);
}

// ------- mean pool (batch sorted, 32 nodes/wave) + logits -----------------------
__global__ __launch_bounds__(256) void k_pool(const float* __restrict__ h2,
                                              const int* __restrict__ batch,
                                              float* __restrict__ pooled,
                                              float* __restrict__ cnt, int N) {
    int wave = (blockIdx.x * 256 + threadIdx.x) >> 6;
    int lane = threadIdx.x & 63;
    int n0 = wave * 32;
    if (n0 >= N) return;
    int n1 = min(n0 + 32, N);
    float acc = 0.f; int cl = 0;
    int curg = batch[n0];
    for (int n = n0; n < n1; n++) {
        int g = batch[n];
        if (g != curg) {
            atomicAdd(&pooled[curg * 64 + lane], acc);
            if (lane == 0) atomicAdd(&cnt[curg], (float)cl);
            acc = 0.f; cl = 0; curg = g;
        }
        acc += h2[(size_t)n * 64 + lane];
        cl++;
    }
    atomicAdd(&pooled[curg * 64 + lane], acc);
    if (lane == 0) atomicAdd(&cnt[curg], (float)cl);
}

__global__ __launch_bounds__(64) void k_logits(const float* __restrict__ pooled,
                                               const float* __restrict__ cnt,
                                               const float* __restrict__ fcW,
                                               const float* __restrict__ fcb,
                                               float* __restrict__ out) {
    int t = threadIdx.x;
    if (t >= NG * 2) return;
    int g = t >> 1, o = t & 1;
    float invc = 1.f / fmaxf(cnt[g], 1.f);
    float s = 0.f;
    for (int c = 0; c < 64; c++)
        s += pooled[g * 64 + c] * invc * fcW[c * 2 + o];
    s += fcb[o];
    out[g * 2 + o] = s;
}

extern "C" void kernel_launch(void* const* d_in, const int* in_sizes, int n_in,
                              void* d_out, int out_size, void* d_ws, size_t ws_size,
                              hipStream_t stream) {
    const float* x     = (const float*)d_in[0];
    const int*   ei    = (const int*)d_in[1];
    const int*   batch = (const int*)d_in[2];
    const float* W1    = (const float*)d_in[3];
    const float* as1   = (const float*)d_in[4];
    const float* ad1   = (const float*)d_in[5];
    const float* b1    = (const float*)d_in[6];
    const float* W2    = (const float*)d_in[7];
    const float* as2   = (const float*)d_in[8];
    const float* ad2   = (const float*)d_in[9];
    const float* b2v   = (const float*)d_in[10];
    const float* fcW   = (const float*)d_in[11];
    const float* fcb   = (const float*)d_in[12];
    float* out = (float*)d_out;

    const int N = in_sizes[2];       // 50000
    const int E = in_sizes[1] / 2;   // 800000
    const size_t nv  = (size_t)N * 64;
    const size_t nv4 = (size_t)N * 256;
    const int SB = (N + 1023) / 1024;

    // workspace layout (floats then ints); ~68 MB
    float*    ws     = (float*)d_ws;
    float*    xw1    = ws;                       // nv4
    float*    xw2    = xw1 + nv4;                // nv
    float*    al4    = xw2 + nv;                 // N*4
    float*    ar4    = al4 + (size_t)N * 4;      // N*4
    float*    al2    = ar4 + (size_t)N * 4;      // N
    float*    ar2    = al2 + N;                  // N
    float*    pooled = ar2 + N;                  // 512
    float*    cnt    = pooled + NG * 64;         // 8
    int*      deg    = (int*)(cnt + 8);          // N
    int*      rp     = deg + N;                  // N+1
    int*      cur    = rp + N + 1;               // N
    int*      csr    = cur + N;                  // E
    int*      bsum   = csr + E;                  // SB
    int*      boff   = bsum + 64;                // SB

    const int gE  = (E + 255) / 256;
    const int gW  = (int)((nv + 255) / 256);     // one wave per node
    const int gB4 = (N + 3) / 4;
    const int gG1 = (N + 15) / 16;
    const int pw  = (N + 31) / 32;
    const int gP  = (pw * 64 + 255) / 256;

    // ---- CSR build ----
    hipMemsetAsync(deg, 0, (size_t)N * sizeof(int), stream);
    k_hist<<<gE, 256, 0, stream>>>(ei, deg, E);
    k_scanA<<<SB, 256, 0, stream>>>(deg, bsum, N);
    k_scanB<<<1, 64, 0, stream>>>(bsum, boff, rp + N, SB);
    k_scanC<<<SB, 256, 0, stream>>>(deg, boff, rp, cur, N);
    k_fill<<<gE, 256, 0, stream>>>(ei, cur, csr, E);

    // ---- layer 1 ----
    k_gemm1<<<gG1, 256, 0, stream>>>(x, W1, as1, ad1, xw1, al4, ar4, N);
    k_agg4<<<gB4, 256, 0, stream>>>(rp, csr, al4, ar4, xw1, b1, W2, as2, ad2,
                                    xw2, al2, ar2, N);

    // ---- layer 2 ----
    k_agg2<<<gW, 256, 0, stream>>>(rp, csr, al2, ar2, xw2, b2v, out, N);

    // ---- pooling + logits ----
    hipMemsetAsync(pooled, 0, (NG * 64 + NG) * sizeof(float), stream);
    k_pool<<<gP, 256, 0, stream>>>(out, batch, pooled, cnt, N);
    k_logits<<<1, 64, 0, stream>>>(pooled, cnt, fcW, fcb, out + nv);
}

// Round 8
// 572.405 us; speedup vs baseline: 7.5834x; 1.0480x over previous
//
#include <hip/hip_runtime.h>

#define NEG_SLOPE 0.2f
#define NG 8

__device__ __forceinline__ float lrelu(float x) { return x > 0.f ? x : NEG_SLOPE * x; }
__device__ __forceinline__ float eluf(float x) { return x > 0.f ? x : expm1f(x); }
__device__ __forceinline__ float wave_sum(float v) {
    #pragma unroll
    for (int o = 32; o; o >>= 1) v += __shfl_xor(v, o);
    return v;
}
// f32 <-> bf16 (RNE), finite inputs only
__device__ __forceinline__ unsigned short f2bf(float f) {
    unsigned u = __float_as_uint(f);
    unsigned r = (u + 0x7FFFu + ((u >> 16) & 1u)) >> 16;
    return (unsigned short)r;
}
__device__ __forceinline__ float bf2f(unsigned short s) {
    return __uint_as_float(((unsigned)s) << 16);
}

// ---------------- CSR build ----------------------------------------------------
__global__ __launch_bounds__(256) void k_hist(const int* __restrict__ ei,
                                              int* __restrict__ deg, int E) {
    int e = blockIdx.x * 256 + threadIdx.x;
    if (e < E) atomicAdd(&deg[ei[E + e]], 1);
}

__global__ __launch_bounds__(256) void k_scanA(const int* __restrict__ deg,
                                               int* __restrict__ bsum, int N) {
    __shared__ int wsums[4];
    int b = blockIdx.x, t = threadIdx.x;
    int base = b * 1024 + t * 4;
    int s = 0;
    #pragma unroll
    for (int k = 0; k < 4; k++) { int i = base + k; if (i < N) s += deg[i]; }
    #pragma unroll
    for (int o = 32; o; o >>= 1) s += __shfl_xor(s, o);
    if ((t & 63) == 0) wsums[t >> 6] = s;
    __syncthreads();
    if (t == 0) bsum[b] = wsums[0] + wsums[1] + wsums[2] + wsums[3];
}

__global__ __launch_bounds__(64) void k_scanB(const int* __restrict__ bsum,
                                              int* __restrict__ boff,
                                              int* __restrict__ rpN, int SB) {
    int lane = threadIdx.x;
    int own = (lane < SB) ? bsum[lane] : 0;
    int v = own;
    #pragma unroll
    for (int o = 1; o < 64; o <<= 1) { int y = __shfl_up(v, o); if (lane >= o) v += y; }
    if (lane < SB) boff[lane] = v - own;
    if (lane == 63) *rpN = v;
}

__global__ __launch_bounds__(256) void k_scanC(const int* __restrict__ deg,
                                               const int* __restrict__ boff,
                                               int* __restrict__ rp,
                                               int* __restrict__ cur, int N) {
    __shared__ int wtot[4];
    int b = blockIdx.x, t = threadIdx.x;
    int wid = t >> 6, lane = t & 63;
    int base = b * 1024 + t * 4;
    int d[4];
    #pragma unroll
    for (int k = 0; k < 4; k++) d[k] = (base + k < N) ? deg[base + k] : 0;
    int tsum = d[0] + d[1] + d[2] + d[3];
    int v = tsum;
    #pragma unroll
    for (int o = 1; o < 64; o <<= 1) { int y = __shfl_up(v, o); if (lane >= o) v += y; }
    if (lane == 63) wtot[wid] = v;
    __syncthreads();
    int wbase = 0;
    for (int k = 0; k < wid; k++) wbase += wtot[k];
    int run = boff[b] + wbase + v - tsum;
    #pragma unroll
    for (int k = 0; k < 4; k++) {
        if (base + k < N) { rp[base + k] = run; cur[base + k] = run; }
        run += d[k];
    }
}

__global__ __launch_bounds__(256) void k_fill(const int* __restrict__ ei,
                                              int* __restrict__ cur,
                                              int* __restrict__ csr, int E) {
    int e = blockIdx.x * 256 + threadIdx.x;
    if (e >= E) return;
    int s = ei[e], d = ei[E + e];
    int pos = atomicAdd(&cur[d], 1);
    csr[pos] = s;
}

// ------- GEMM1: xw1(bf16) = x @ W1, fused per-head al/ar epilogue (f32-exact) ---
__global__ __launch_bounds__(256) void k_gemm1(const float* __restrict__ x,
                                               const float* __restrict__ W1,
                                               const float* __restrict__ a_s,
                                               const float* __restrict__ a_d,
                                               unsigned short* __restrict__ xw1b,
                                               float* __restrict__ al4,
                                               float* __restrict__ ar4, int N) {
    __shared__ float As[16][256];
    int r0 = blockIdx.x * 16;
    int lane = threadIdx.x & 63, rq = threadIdx.x >> 6;
    int c4 = lane << 2;
    for (int i = threadIdx.x; i < 1024; i += 256) {
        int r = i >> 6, k4 = (i & 63) << 2;
        float4 v = (r0 + r < N) ? *(const float4*)(x + (size_t)(r0 + r) * 256 + k4)
                                : make_float4(0.f, 0.f, 0.f, 0.f);
        As[r][k4] = v.x; As[r][k4 + 1] = v.y; As[r][k4 + 2] = v.z; As[r][k4 + 3] = v.w;
    }
    __syncthreads();
    float4 acc[4];
    #pragma unroll
    for (int t = 0; t < 4; t++) acc[t] = make_float4(0.f, 0.f, 0.f, 0.f);
    for (int k4 = 0; k4 < 256; k4 += 4) {
        float4 w0 = *(const float4*)(W1 + (size_t)(k4 + 0) * 256 + c4);
        float4 w1 = *(const float4*)(W1 + (size_t)(k4 + 1) * 256 + c4);
        float4 w2 = *(const float4*)(W1 + (size_t)(k4 + 2) * 256 + c4);
        float4 w3 = *(const float4*)(W1 + (size_t)(k4 + 3) * 256 + c4);
        #pragma unroll
        for (int t = 0; t < 4; t++) {
            float4 a = *(const float4*)(&As[rq + 4 * t][k4]);
            acc[t].x += a.x * w0.x + a.y * w1.x + a.z * w2.x + a.w * w3.x;
            acc[t].y += a.x * w0.y + a.y * w1.y + a.z * w2.y + a.w * w3.y;
            acc[t].z += a.x * w0.z + a.y * w1.z + a.z * w2.z + a.w * w3.z;
            acc[t].w += a.x * w0.w + a.y * w1.w + a.z * w2.w + a.w * w3.w;
        }
    }
    #pragma unroll
    for (int t = 0; t < 4; t++) {
        int r = r0 + rq + 4 * t;
        if (r < N) {
            ushort4 o;
            o.x = f2bf(acc[t].x); o.y = f2bf(acc[t].y);
            o.z = f2bf(acc[t].z); o.w = f2bf(acc[t].w);
            *(ushort4*)(xw1b + (size_t)r * 256 + c4) = o;
        }
    }
    // fused al/ar from exact f32 acc: head h = lane>>4, cols kk..kk+3
    int h = lane >> 4, kk = c4 & 63;
    float4 s4 = *(const float4*)(a_s + h * 64 + kk);
    float4 d4 = *(const float4*)(a_d + h * 64 + kk);
    #pragma unroll
    for (int t = 0; t < 4; t++) {
        float sl = acc[t].x * s4.x + acc[t].y * s4.y + acc[t].z * s4.z + acc[t].w * s4.w;
        float sr = acc[t].x * d4.x + acc[t].y * d4.y + acc[t].z * d4.z + acc[t].w * d4.w;
        #pragma unroll
        for (int o = 1; o < 16; o <<= 1) { sl += __shfl_xor(sl, o); sr += __shfl_xor(sr, o); }
        int r = r0 + rq + 4 * t;
        if ((lane & 15) == 0 && r < N) {
            al4[(size_t)r * 4 + h] = sl;
            ar4[(size_t)r * 4 + h] = sr;
        }
    }
}

__device__ __forceinline__ float4 wexp4(float4 a, float4 arn) {
    float4 w;
    w.x = __expf(lrelu(a.x + arn.x));
    w.y = __expf(lrelu(a.y + arn.y));
    w.z = __expf(lrelu(a.z + arn.z));
    w.w = __expf(lrelu(a.w + arn.w));
    return w;
}

// ------- layer-1 aggregate (4 heads, bf16 rows) + ELU/b1 + GEMM2 + alar2 --------
__global__ __launch_bounds__(256) void k_agg4(const int* __restrict__ rp,
                                              const int* __restrict__ csr,
                                              const float* __restrict__ al4,
                                              const float* __restrict__ ar4,
                                              const unsigned short* __restrict__ xw1b,
                                              const float* __restrict__ b1,
                                              const float* __restrict__ W2,
                                              const float* __restrict__ as2,
                                              const float* __restrict__ ad2,
                                              float* __restrict__ xw2,
                                              float* __restrict__ al2,
                                              float* __restrict__ ar2, int N) {
    __shared__ float hs[4][256];
    int wIdx = threadIdx.x >> 6;
    int n = (blockIdx.x * 256 + threadIdx.x) >> 6;
    int lane = threadIdx.x & 63;
    bool act = n < N;
    if (act) {
        int e0 = rp[n], e1 = rp[n + 1];
        float4 arn = *(const float4*)(ar4 + (size_t)n * 4);
        float4 aln = *(const float4*)(al4 + (size_t)n * 4);
        float4 wsf = wexp4(aln, arn);           // self-loop weight
        const unsigned short* xr = xw1b + (size_t)n * 256;
        float a0 = wsf.x * bf2f(xr[lane]);
        float a1 = wsf.y * bf2f(xr[64 + lane]);
        float a2 = wsf.z * bf2f(xr[128 + lane]);
        float a3 = wsf.w * bf2f(xr[192 + lane]);
        float wx = wsf.x, wy = wsf.y, wz = wsf.z, ww = wsf.w;
        int j = e0;
        for (; j + 4 <= e1; j += 4) {
            int s0 = csr[j], s1 = csr[j + 1], s2 = csr[j + 2], s3 = csr[j + 3];
            float4 A0 = *(const float4*)(al4 + (size_t)s0 * 4);
            float4 A1 = *(const float4*)(al4 + (size_t)s1 * 4);
            float4 A2 = *(const float4*)(al4 + (size_t)s2 * 4);
            float4 A3 = *(const float4*)(al4 + (size_t)s3 * 4);
            const unsigned short* r0_ = xw1b + (size_t)s0 * 256;
            const unsigned short* r1_ = xw1b + (size_t)s1 * 256;
            const unsigned short* r2_ = xw1b + (size_t)s2 * 256;
            const unsigned short* r3_ = xw1b + (size_t)s3 * 256;
            float v00 = bf2f(r0_[lane]), v01 = bf2f(r0_[64 + lane]), v02 = bf2f(r0_[128 + lane]), v03 = bf2f(r0_[192 + lane]);
            float v10 = bf2f(r1_[lane]), v11 = bf2f(r1_[64 + lane]), v12 = bf2f(r1_[128 + lane]), v13 = bf2f(r1_[192 + lane]);
            float v20 = bf2f(r2_[lane]), v21 = bf2f(r2_[64 + lane]), v22 = bf2f(r2_[128 + lane]), v23 = bf2f(r2_[192 + lane]);
            float v30 = bf2f(r3_[lane]), v31 = bf2f(r3_[64 + lane]), v32 = bf2f(r3_[128 + lane]), v33 = bf2f(r3_[192 + lane]);
            float4 w0 = wexp4(A0, arn), w1 = wexp4(A1, arn), w2 = wexp4(A2, arn), w3 = wexp4(A3, arn);
            wx += w0.x + w1.x + w2.x + w3.x;
            wy += w0.y + w1.y + w2.y + w3.y;
            wz += w0.z + w1.z + w2.z + w3.z;
            ww += w0.w + w1.w + w2.w + w3.w;
            a0 += w0.x * v00 + w1.x * v10 + w2.x * v20 + w3.x * v30;
            a1 += w0.y * v01 + w1.y * v11 + w2.y * v21 + w3.y * v31;
            a2 += w0.z * v02 + w1.z * v12 + w2.z * v22 + w3.z * v32;
            a3 += w0.w * v03 + w1.w * v13 + w2.w * v23 + w3.w * v33;
        }
        for (; j < e1; j++) {
            int s = csr[j];
            float4 A = *(const float4*)(al4 + (size_t)s * 4);
            const unsigned short* r_ = xw1b + (size_t)s * 256;
            float4 w = wexp4(A, arn);
            wx += w.x; wy += w.y; wz += w.z; ww += w.w;
            a0 += w.x * bf2f(r_[lane]);
            a1 += w.y * bf2f(r_[64 + lane]);
            a2 += w.z * bf2f(r_[128 + lane]);
            a3 += w.w * bf2f(r_[192 + lane]);
        }
        hs[wIdx][lane]       = eluf(a0 / wx + b1[lane]);
        hs[wIdx][64 + lane]  = eluf(a1 / wy + b1[64 + lane]);
        hs[wIdx][128 + lane] = eluf(a2 / wz + b1[128 + lane]);
        hs[wIdx][192 + lane] = eluf(a3 / ww + b1[192 + lane]);
    }
    __syncthreads();
    if (act) {
        float acc2 = 0.f;
        #pragma unroll 4
        for (int k = 0; k < 256; k++)
            acc2 += hs[wIdx][k] * W2[(size_t)k * 64 + lane];
        xw2[(size_t)n * 64 + lane] = acc2;
        float sl = wave_sum(acc2 * as2[lane]);
        float sr = wave_sum(acc2 * ad2[lane]);
        if (lane == 0) { al2[n] = sl; ar2[n] = sr; }
    }
}

// ------- layer-2 aggregate + ELU, writes h straight to d_out (f32 xw2) ----------
__global__ __launch_bounds__(256) void k_agg2(const int* __restrict__ rp,
                                              const int* __restrict__ csr,
                                              const float* __restrict__ al2,
                                              const float* __restrict__ ar2,
                                              const float* __restrict__ xw2,
                                              const float* __restrict__ b2,
                                              float* __restrict__ hout, int N) {
    int n = (blockIdx.x * 256 + threadIdx.x) >> 6;
    int lane = threadIdx.x & 63;
    if (n >= N) return;
    int e0 = rp[n], e1 = rp[n + 1];
    float arn = ar2[n];
    float wself = __expf(lrelu(al2[n] + arn));
    float acc = wself * xw2[(size_t)n * 64 + lane];
    float wsum = wself;
    int j = e0;
    for (; j + 4 <= e1; j += 4) {
        int s0 = csr[j], s1 = csr[j + 1], s2 = csr[j + 2], s3 = csr[j + 3];
        float A0 = al2[s0], A1 = al2[s1], A2 = al2[s2], A3 = al2[s3];
        float v0 = xw2[(size_t)s0 * 64 + lane];
        float v1 = xw2[(size_t)s1 * 64 + lane];
        float v2 = xw2[(size_t)s2 * 64 + lane];
        float v3 = xw2[(size_t)s3 * 64 + lane];
        float w0 = __expf(lrelu(A0 + arn));
        float w1 = __expf(lrelu(A1 + arn));
        float w2 = __expf(lrelu(A2 + arn));
        float w3 = __expf(lrelu(A3 + arn));
        wsum += w0 + w1 + w2 + w3;
        acc += w0 * v0 + w1 * v1 + w2 * v2 + w3 * v3;
    }
    for (; j < e1; j++) {
        int s = csr[j];
        float w = __expf(lrelu(al2[s] + arn));
        wsum += w;
        acc += w * xw2[(size_t)s * 64 + lane];
    }
    hout[(size_t)n * 64 + lane] = eluf(acc / wsum + b2[lane]);
}

// ------- mean pool (batch sorted, 32 nodes/wave) + logits -----------------------
__global__ __launch_bounds__(256) void k_pool(const float* __restrict__ h2,
                                              const int* __restrict__ batch,
                                              float* __restrict__ pooled,
                                              float* __restrict__ cnt, int N) {
    int wave = (blockIdx.x * 256 + threadIdx.x) >> 6;
    int lane = threadIdx.x & 63;
    int n0 = wave * 32;
    if (n0 >= N) return;
    int n1 = min(n0 + 32, N);
    float acc = 0.f; int cl = 0;
    int curg = batch[n0];
    for (int n = n0; n < n1; n++) {
        int g = batch[n];
        if (g != curg) {
            atomicAdd(&pooled[curg * 64 + lane], acc);
            if (lane == 0) atomicAdd(&cnt[curg], (float)cl);
            acc = 0.f; cl = 0; curg = g;
        }
        acc += h2[(size_t)n * 64 + lane];
        cl++;
    }
    atomicAdd(&pooled[curg * 64 + lane], acc);
    if (lane == 0) atomicAdd(&cnt[curg], (float)cl);
}

__global__ __launch_bounds__(64) void k_logits(const float* __restrict__ pooled,
                                               const float* __restrict__ cnt,
                                               const float* __restrict__ fcW,
                                               const float* __restrict__ fcb,
                                               float* __restrict__ out) {
    int t = threadIdx.x;
    if (t >= NG * 2) return;
    int g = t >> 1, o = t & 1;
    float invc = 1.f / fmaxf(cnt[g], 1.f);
    float s = 0.f;
    for (int c = 0; c < 64; c++)
        s += pooled[g * 64 + c] * invc * fcW[c * 2 + o];
    s += fcb[o];
    out[g * 2 + o] = s;
}

extern "C" void kernel_launch(void* const* d_in, const int* in_sizes, int n_in,
                              void* d_out, int out_size, void* d_ws, size_t ws_size,
                              hipStream_t stream) {
    const float* x     = (const float*)d_in[0];
    const int*   ei    = (const int*)d_in[1];
    const int*   batch = (const int*)d_in[2];
    const float* W1    = (const float*)d_in[3];
    const float* as1   = (const float*)d_in[4];
    const float* ad1   = (const float*)d_in[5];
    const float* b1    = (const float*)d_in[6];
    const float* W2    = (const float*)d_in[7];
    const float* as2   = (const float*)d_in[8];
    const float* ad2   = (const float*)d_in[9];
    const float* b2v   = (const float*)d_in[10];
    const float* fcW   = (const float*)d_in[11];
    const float* fcb   = (const float*)d_in[12];
    float* out = (float*)d_out;

    const int N = in_sizes[2];       // 50000
    const int E = in_sizes[1] / 2;   // 800000
    const size_t nv  = (size_t)N * 64;
    const size_t nv4 = (size_t)N * 256;
    const int SB = (N + 1023) / 1024;

    // workspace layout: bf16 xw1 first, then floats, then ints (~45 MB)
    unsigned short* xw1b = (unsigned short*)d_ws;          // nv4 ushorts (25.6 MB)
    float*    xw2    = (float*)(xw1b + nv4);               // nv
    float*    al4    = xw2 + nv;                           // N*4
    float*    ar4    = al4 + (size_t)N * 4;                // N*4
    float*    al2    = ar4 + (size_t)N * 4;                // N
    float*    ar2    = al2 + N;                            // N
    float*    pooled = ar2 + N;                            // 512
    float*    cnt    = pooled + NG * 64;                   // 8
    int*      deg    = (int*)(cnt + 8);                    // N
    int*      rp     = deg + N;                            // N+1
    int*      cur    = rp + N + 1;                         // N
    int*      csr    = cur + N;                            // E
    int*      bsum   = csr + E;                            // SB
    int*      boff   = bsum + 64;                          // SB

    const int gE  = (E + 255) / 256;
    const int gW  = (int)((nv + 255) / 256);     // one wave per node
    const int gB4 = (N + 3) / 4;
    const int gG1 = (N + 15) / 16;
    const int pw  = (N + 31) / 32;
    const int gP  = (pw * 64 + 255) / 256;

    // ---- CSR build ----
    hipMemsetAsync(deg, 0, (size_t)N * sizeof(int), stream);
    k_hist<<<gE, 256, 0, stream>>>(ei, deg, E);
    k_scanA<<<SB, 256, 0, stream>>>(deg, bsum, N);
    k_scanB<<<1, 64, 0, stream>>>(bsum, boff, rp + N, SB);
    k_scanC<<<SB, 256, 0, stream>>>(deg, boff, rp, cur, N);
    k_fill<<<gE, 256, 0, stream>>>(ei, cur, csr, E);

    // ---- layer 1 ----
    k_gemm1<<<gG1, 256, 0, stream>>>(x, W1, as1, ad1, xw1b, al4, ar4, N);
    k_agg4<<<gB4, 256, 0, stream>>>(rp, csr, al4, ar4, xw1b, b1, W2, as2, ad2,
                                    xw2, al2, ar2, N);

    // ---- layer 2 ----
    k_agg2<<<gW, 256, 0, stream>>>(rp, csr, al2, ar2, xw2, b2v, out, N);

    // ---- pooling + logits ----
    hipMemsetAsync(pooled, 0, (NG * 64 + NG) * sizeof(float), stream);
    k_pool<<<gP, 256, 0, stream>>>(out, batch, pooled, cnt, N);
    k_logits<<<1, 64, 0, stream>>>(pooled, cnt, fcW, fcb, out + nv);
}

// Round 9
// 557.578 us; speedup vs baseline: 7.7850x; 1.0266x over previous
//
#include <hip/hip_runtime.h>

#define NEG_SLOPE 0.2f
#define NG 8
#define CH 64   // edge chunk per wave (lane-parallel weight phase)

typedef unsigned short ushort_t;

__device__ __forceinline__ float lrelu(float x) { return x > 0.f ? x : NEG_SLOPE * x; }
__device__ __forceinline__ float eluf(float x) { return x > 0.f ? x : expm1f(x); }
__device__ __forceinline__ float wave_sum(float v) {
    #pragma unroll
    for (int o = 32; o; o >>= 1) v += __shfl_xor(v, o);
    return v;
}
// f32 <-> bf16 (RNE), finite inputs only
__device__ __forceinline__ ushort_t f2bf(float f) {
    unsigned u = __float_as_uint(f);
    unsigned r = (u + 0x7FFFu + ((u >> 16) & 1u)) >> 16;
    return (ushort_t)r;
}
__device__ __forceinline__ float bf2f(ushort_t s) {
    return __uint_as_float(((unsigned)s) << 16);
}

// ---------------- CSR build ----------------------------------------------------
__global__ __launch_bounds__(256) void k_hist(const int* __restrict__ ei,
                                              int* __restrict__ deg, int E) {
    int e = blockIdx.x * 256 + threadIdx.x;
    if (e < E) atomicAdd(&deg[ei[E + e]], 1);
}

__global__ __launch_bounds__(256) void k_scanA(const int* __restrict__ deg,
                                               int* __restrict__ bsum, int N) {
    __shared__ int wsums[4];
    int b = blockIdx.x, t = threadIdx.x;
    int base = b * 1024 + t * 4;
    int s = 0;
    #pragma unroll
    for (int k = 0; k < 4; k++) { int i = base + k; if (i < N) s += deg[i]; }
    #pragma unroll
    for (int o = 32; o; o >>= 1) s += __shfl_xor(s, o);
    if ((t & 63) == 0) wsums[t >> 6] = s;
    __syncthreads();
    if (t == 0) bsum[b] = wsums[0] + wsums[1] + wsums[2] + wsums[3];
}

__global__ __launch_bounds__(64) void k_scanB(const int* __restrict__ bsum,
                                              int* __restrict__ boff,
                                              int* __restrict__ rpN, int SB) {
    int lane = threadIdx.x;
    int own = (lane < SB) ? bsum[lane] : 0;
    int v = own;
    #pragma unroll
    for (int o = 1; o < 64; o <<= 1) { int y = __shfl_up(v, o); if (lane >= o) v += y; }
    if (lane < SB) boff[lane] = v - own;
    if (lane == 63) *rpN = v;
}

__global__ __launch_bounds__(256) void k_scanC(const int* __restrict__ deg,
                                               const int* __restrict__ boff,
                                               int* __restrict__ rp,
                                               int* __restrict__ cur, int N) {
    __shared__ int wtot[4];
    int b = blockIdx.x, t = threadIdx.x;
    int wid = t >> 6, lane = t & 63;
    int base = b * 1024 + t * 4;
    int d[4];
    #pragma unroll
    for (int k = 0; k < 4; k++) d[k] = (base + k < N) ? deg[base + k] : 0;
    int tsum = d[0] + d[1] + d[2] + d[3];
    int v = tsum;
    #pragma unroll
    for (int o = 1; o < 64; o <<= 1) { int y = __shfl_up(v, o); if (lane >= o) v += y; }
    if (lane == 63) wtot[wid] = v;
    __syncthreads();
    int wbase = 0;
    for (int k = 0; k < wid; k++) wbase += wtot[k];
    int run = boff[b] + wbase + v - tsum;
    #pragma unroll
    for (int k = 0; k < 4; k++) {
        if (base + k < N) { rp[base + k] = run; cur[base + k] = run; }
        run += d[k];
    }
}

__global__ __launch_bounds__(256) void k_fill(const int* __restrict__ ei,
                                              int* __restrict__ cur,
                                              int* __restrict__ csr, int E) {
    int e = blockIdx.x * 256 + threadIdx.x;
    if (e >= E) return;
    int s = ei[e], d = ei[E + e];
    int pos = atomicAdd(&cur[d], 1);
    csr[pos] = s;
}

// ------- GEMM1: xw1(bf16, head-interleaved [k*4+h]) = x @ W1 + al/ar epilogue ---
__global__ __launch_bounds__(256) void k_gemm1(const float* __restrict__ x,
                                               const float* __restrict__ W1,
                                               const float* __restrict__ a_s,
                                               const float* __restrict__ a_d,
                                               ushort_t* __restrict__ xw1b,
                                               float* __restrict__ al4,
                                               float* __restrict__ ar4, int N) {
    __shared__ float As[16][256];   // 16 KB; reused as ushort[16][256] for repack
    int r0 = blockIdx.x * 16;
    int lane = threadIdx.x & 63, rq = threadIdx.x >> 6;
    int c4 = lane << 2;
    for (int i = threadIdx.x; i < 1024; i += 256) {
        int r = i >> 6, k4 = (i & 63) << 2;
        float4 v = (r0 + r < N) ? *(const float4*)(x + (size_t)(r0 + r) * 256 + k4)
                                : make_float4(0.f, 0.f, 0.f, 0.f);
        As[r][k4] = v.x; As[r][k4 + 1] = v.y; As[r][k4 + 2] = v.z; As[r][k4 + 3] = v.w;
    }
    __syncthreads();
    float4 acc[4];
    #pragma unroll
    for (int t = 0; t < 4; t++) acc[t] = make_float4(0.f, 0.f, 0.f, 0.f);
    for (int k4 = 0; k4 < 256; k4 += 4) {
        float4 w0 = *(const float4*)(W1 + (size_t)(k4 + 0) * 256 + c4);
        float4 w1 = *(const float4*)(W1 + (size_t)(k4 + 1) * 256 + c4);
        float4 w2 = *(const float4*)(W1 + (size_t)(k4 + 2) * 256 + c4);
        float4 w3 = *(const float4*)(W1 + (size_t)(k4 + 3) * 256 + c4);
        #pragma unroll
        for (int t = 0; t < 4; t++) {
            float4 a = *(const float4*)(&As[rq + 4 * t][k4]);
            acc[t].x += a.x * w0.x + a.y * w1.x + a.z * w2.x + a.w * w3.x;
            acc[t].y += a.x * w0.y + a.y * w1.y + a.z * w2.y + a.w * w3.y;
            acc[t].z += a.x * w0.z + a.y * w1.z + a.z * w2.z + a.w * w3.z;
            acc[t].w += a.x * w0.w + a.y * w1.w + a.z * w2.w + a.w * w3.w;
        }
    }
    // fused al/ar from exact f32 acc: head h = lane>>4, cols kk..kk+3
    int h = lane >> 4, kk = c4 & 63;
    float4 s4 = *(const float4*)(a_s + h * 64 + kk);
    float4 d4 = *(const float4*)(a_d + h * 64 + kk);
    #pragma unroll
    for (int t = 0; t < 4; t++) {
        float sl = acc[t].x * s4.x + acc[t].y * s4.y + acc[t].z * s4.z + acc[t].w * s4.w;
        float sr = acc[t].x * d4.x + acc[t].y * d4.y + acc[t].z * d4.z + acc[t].w * d4.w;
        #pragma unroll
        for (int o = 1; o < 16; o <<= 1) { sl += __shfl_xor(sl, o); sr += __shfl_xor(sr, o); }
        int r = r0 + rq + 4 * t;
        if ((lane & 15) == 0 && r < N) {
            al4[(size_t)r * 4 + h] = sl;
            ar4[(size_t)r * 4 + h] = sr;
        }
    }
    // repack to head-interleaved bf16 via LDS, then coalesced stores
    __syncthreads();                       // all waves done reading As
    ushort_t* Ls = (ushort_t*)As;          // [16][256] ushorts = 8 KB
    #pragma unroll
    for (int t = 0; t < 4; t++) {
        int rl = rq + 4 * t;
        Ls[rl * 256 + (kk + 0) * 4 + h] = f2bf(acc[t].x);
        Ls[rl * 256 + (kk + 1) * 4 + h] = f2bf(acc[t].y);
        Ls[rl * 256 + (kk + 2) * 4 + h] = f2bf(acc[t].z);
        Ls[rl * 256 + (kk + 3) * 4 + h] = f2bf(acc[t].w);
    }
    __syncthreads();
    #pragma unroll
    for (int p = 0; p < 2; p++) {
        int flat = p * 2048 + threadIdx.x * 8;     // 8 ushorts = 16 B per thread
        int rl = flat >> 8, col = flat & 255;
        int r = r0 + rl;
        if (r < N)
            *(uint4*)(xw1b + (size_t)r * 256 + col) = *(const uint4*)(Ls + flat);
    }
}

__device__ __forceinline__ float4 wexp4(float4 a, float4 arn) {
    float4 w;
    w.x = __expf(lrelu(a.x + arn.x));
    w.y = __expf(lrelu(a.y + arn.y));
    w.z = __expf(lrelu(a.z + arn.z));
    w.w = __expf(lrelu(a.w + arn.w));
    return w;
}

// ------- layer-1 aggregate: two-phase (lane-parallel weights, serial gather) ----
__global__ __launch_bounds__(256) void k_agg4(const int* __restrict__ rp,
                                              const int* __restrict__ csr,
                                              const float* __restrict__ al4,
                                              const float* __restrict__ ar4,
                                              const ushort_t* __restrict__ xw1b,
                                              const float* __restrict__ b1,
                                              const float* __restrict__ W2,
                                              const float* __restrict__ as2,
                                              const float* __restrict__ ad2,
                                              float* __restrict__ xw2,
                                              float* __restrict__ al2,
                                              float* __restrict__ ar2, int N) {
    __shared__ float hs[4][256];
    __shared__ float4 wbuf[4][CH];
    __shared__ int sbuf[4][CH];
    int wIdx = threadIdx.x >> 6;
    int n = (blockIdx.x * 256 + threadIdx.x) >> 6;
    int lane = threadIdx.x & 63;
    bool act = n < N;
    if (act) {
        int e0 = rp[n], e1 = rp[n + 1];
        float4 arn = *(const float4*)(ar4 + (size_t)n * 4);
        float4 aln = *(const float4*)(al4 + (size_t)n * 4);
        float4 wsf = wexp4(aln, arn);           // self-loop weight
        ushort4 sv = *(const ushort4*)(xw1b + (size_t)n * 256 + lane * 4);
        float a0 = wsf.x * bf2f(sv.x);
        float a1 = wsf.y * bf2f(sv.y);
        float a2 = wsf.z * bf2f(sv.z);
        float a3 = wsf.w * bf2f(sv.w);
        float px = 0.f, py = 0.f, pz = 0.f, pw = 0.f;   // lane-partial weight sums
        for (int cs = e0; cs < e1; cs += CH) {
            int cnt = min(CH, e1 - cs);
            if (lane < cnt) {
                int s = csr[cs + lane];
                float4 A = *(const float4*)(al4 + (size_t)s * 4);
                float4 w = wexp4(A, arn);
                sbuf[wIdx][lane] = s;
                wbuf[wIdx][lane] = w;
                px += w.x; py += w.y; pz += w.z; pw += w.w;
            }
            // drain LDS writes; per-wave LDS is in-order, no block barrier needed
            asm volatile("s_waitcnt lgkmcnt(0)" ::: "memory");
            int jj = 0;
            for (; jj + 4 <= cnt; jj += 4) {
                int s0 = sbuf[wIdx][jj],     s1 = sbuf[wIdx][jj + 1];
                int s2 = sbuf[wIdx][jj + 2], s3 = sbuf[wIdx][jj + 3];
                float4 w0 = wbuf[wIdx][jj],     w1 = wbuf[wIdx][jj + 1];
                float4 w2 = wbuf[wIdx][jj + 2], w3 = wbuf[wIdx][jj + 3];
                ushort4 v0 = *(const ushort4*)(xw1b + (size_t)s0 * 256 + lane * 4);
                ushort4 v1 = *(const ushort4*)(xw1b + (size_t)s1 * 256 + lane * 4);
                ushort4 v2 = *(const ushort4*)(xw1b + (size_t)s2 * 256 + lane * 4);
                ushort4 v3 = *(const ushort4*)(xw1b + (size_t)s3 * 256 + lane * 4);
                a0 += w0.x * bf2f(v0.x) + w1.x * bf2f(v1.x) + w2.x * bf2f(v2.x) + w3.x * bf2f(v3.x);
                a1 += w0.y * bf2f(v0.y) + w1.y * bf2f(v1.y) + w2.y * bf2f(v2.y) + w3.y * bf2f(v3.y);
                a2 += w0.z * bf2f(v0.z) + w1.z * bf2f(v1.z) + w2.z * bf2f(v2.z) + w3.z * bf2f(v3.z);
                a3 += w0.w * bf2f(v0.w) + w1.w * bf2f(v1.w) + w2.w * bf2f(v2.w) + w3.w * bf2f(v3.w);
            }
            for (; jj < cnt; jj++) {
                int s = sbuf[wIdx][jj];
                float4 w = wbuf[wIdx][jj];
                ushort4 v = *(const ushort4*)(xw1b + (size_t)s * 256 + lane * 4);
                a0 += w.x * bf2f(v.x);
                a1 += w.y * bf2f(v.y);
                a2 += w.z * bf2f(v.z);
                a3 += w.w * bf2f(v.w);
            }
        }
        float wx = wave_sum(px) + wsf.x;
        float wy = wave_sum(py) + wsf.y;
        float wz = wave_sum(pz) + wsf.z;
        float ww = wave_sum(pw) + wsf.w;
        hs[wIdx][lane]       = eluf(a0 / wx + b1[lane]);
        hs[wIdx][64 + lane]  = eluf(a1 / wy + b1[64 + lane]);
        hs[wIdx][128 + lane] = eluf(a2 / wz + b1[128 + lane]);
        hs[wIdx][192 + lane] = eluf(a3 / ww + b1[192 + lane]);
    }
    __syncthreads();
    if (act) {
        float acc2 = 0.f;
        #pragma unroll 4
        for (int k = 0; k < 256; k++)
            acc2 += hs[wIdx][k] * W2[(size_t)k * 64 + lane];
        xw2[(size_t)n * 64 + lane] = acc2;
        float sl = wave_sum(acc2 * as2[lane]);
        float sr = wave_sum(acc2 * ad2[lane]);
        if (lane == 0) { al2[n] = sl; ar2[n] = sr; }
    }
}

// ------- layer-2 aggregate: same two-phase scheme, writes h to d_out ------------
__global__ __launch_bounds__(256) void k_agg2(const int* __restrict__ rp,
                                              const int* __restrict__ csr,
                                              const float* __restrict__ al2,
                                              const float* __restrict__ ar2,
                                              const float* __restrict__ xw2,
                                              const float* __restrict__ b2,
                                              float* __restrict__ hout, int N) {
    __shared__ float wbuf[4][CH];
    __shared__ int sbuf[4][CH];
    int wIdx = threadIdx.x >> 6;
    int n = (blockIdx.x * 256 + threadIdx.x) >> 6;
    int lane = threadIdx.x & 63;
    if (n >= N) return;
    int e0 = rp[n], e1 = rp[n + 1];
    float arn = ar2[n];
    float wself = __expf(lrelu(al2[n] + arn));
    float acc = wself * xw2[(size_t)n * 64 + lane];
    float p = 0.f;
    for (int cs = e0; cs < e1; cs += CH) {
        int cnt = min(CH, e1 - cs);
        if (lane < cnt) {
            int s = csr[cs + lane];
            float w = __expf(lrelu(al2[s] + arn));
            sbuf[wIdx][lane] = s;
            wbuf[wIdx][lane] = w;
            p += w;
        }
        asm volatile("s_waitcnt lgkmcnt(0)" ::: "memory");
        int jj = 0;
        for (; jj + 4 <= cnt; jj += 4) {
            int s0 = sbuf[wIdx][jj],     s1 = sbuf[wIdx][jj + 1];
            int s2 = sbuf[wIdx][jj + 2], s3 = sbuf[wIdx][jj + 3];
            float w0 = wbuf[wIdx][jj],     w1 = wbuf[wIdx][jj + 1];
            float w2 = wbuf[wIdx][jj + 2], w3 = wbuf[wIdx][jj + 3];
            float v0 = xw2[(size_t)s0 * 64 + lane];
            float v1 = xw2[(size_t)s1 * 64 + lane];
            float v2 = xw2[(size_t)s2 * 64 + lane];
            float v3 = xw2[(size_t)s3 * 64 + lane];
            acc += w0 * v0 + w1 * v1 + w2 * v2 + w3 * v3;
        }
        for (; jj < cnt; jj++) {
            int s = sbuf[wIdx][jj];
            acc += wbuf[wIdx][jj] * xw2[(size_t)s * 64 + lane];
        }
    }
    float wsum = wave_sum(p) + wself;
    hout[(size_t)n * 64 + lane] = eluf(acc / wsum + b2[lane]);
}

// ------- mean pool (batch sorted, 32 nodes/wave) + logits -----------------------
__global__ __launch_bounds__(256) void k_pool(const float* __restrict__ h2,
                                              const int* __restrict__ batch,
                                              float* __restrict__ pooled,
                                              float* __restrict__ cnt, int N) {
    int wave = (blockIdx.x * 256 + threadIdx.x) >> 6;
    int lane = threadIdx.x & 63;
    int n0 = wave * 32;
    if (n0 >= N) return;
    int n1 = min(n0 + 32, N);
    float acc = 0.f; int cl = 0;
    int curg = batch[n0];
    for (int n = n0; n < n1; n++) {
        int g = batch[n];
        if (g != curg) {
            atomicAdd(&pooled[curg * 64 + lane], acc);
            if (lane == 0) atomicAdd(&cnt[curg], (float)cl);
            acc = 0.f; cl = 0; curg = g;
        }
        acc += h2[(size_t)n * 64 + lane];
        cl++;
    }
    atomicAdd(&pooled[curg * 64 + lane], acc);
    if (lane == 0) atomicAdd(&cnt[curg], (float)cl);
}

__global__ __launch_bounds__(64) void k_logits(const float* __restrict__ pooled,
                                               const float* __restrict__ cnt,
                                               const float* __restrict__ fcW,
                                               const float* __restrict__ fcb,
                                               float* __restrict__ out) {
    int t = threadIdx.x;
    if (t >= NG * 2) return;
    int g = t >> 1, o = t & 1;
    float invc = 1.f / fmaxf(cnt[g], 1.f);
    float s = 0.f;
    for (int c = 0; c < 64; c++)
        s += pooled[g * 64 + c] * invc * fcW[c * 2 + o];
    s += fcb[o];
    out[g * 2 + o] = s;
}

extern "C" void kernel_launch(void* const* d_in, const int* in_sizes, int n_in,
                              void* d_out, int out_size, void* d_ws, size_t ws_size,
                              hipStream_t stream) {
    const float* x     = (const float*)d_in[0];
    const int*   ei    = (const int*)d_in[1];
    const int*   batch = (const int*)d_in[2];
    const float* W1    = (const float*)d_in[3];
    const float* as1   = (const float*)d_in[4];
    const float* ad1   = (const float*)d_in[5];
    const float* b1    = (const float*)d_in[6];
    const float* W2    = (const float*)d_in[7];
    const float* as2   = (const float*)d_in[8];
    const float* ad2   = (const float*)d_in[9];
    const float* b2v   = (const float*)d_in[10];
    const float* fcW   = (const float*)d_in[11];
    const float* fcb   = (const float*)d_in[12];
    float* out = (float*)d_out;

    const int N = in_sizes[2];       // 50000
    const int E = in_sizes[1] / 2;   // 800000
    const size_t nv  = (size_t)N * 64;
    const size_t nv4 = (size_t)N * 256;
    const int SB = (N + 1023) / 1024;

    // workspace layout: bf16 xw1 first, then floats, then ints (~45 MB)
    ushort_t* xw1b = (ushort_t*)d_ws;                      // nv4 ushorts (25.6 MB)
    float*    xw2    = (float*)(xw1b + nv4);               // nv
    float*    al4    = xw2 + nv;                           // N*4
    float*    ar4    = al4 + (size_t)N * 4;                // N*4
    float*    al2    = ar4 + (size_t)N * 4;                // N
    float*    ar2    = al2 + N;                            // N
    float*    pooled = ar2 + N;                            // 512
    float*    cnt    = pooled + NG * 64;                   // 8
    int*      deg    = (int*)(cnt + 8);                    // N
    int*      rp     = deg + N;                            // N+1
    int*      cur    = rp + N + 1;                         // N
    int*      csr    = cur + N;                            // E
    int*      bsum   = csr + E;                            // SB
    int*      boff   = bsum + 64;                          // SB

    const int gE  = (E + 255) / 256;
    const int gW  = (int)((nv + 255) / 256);     // one wave per node
    const int gB4 = (N + 3) / 4;
    const int gG1 = (N + 15) / 16;
    const int pw  = (N + 31) / 32;
    const int gP  = (pw * 64 + 255) / 256;

    // ---- CSR build ----
    hipMemsetAsync(deg, 0, (size_t)N * sizeof(int), stream);
    k_hist<<<gE, 256, 0, stream>>>(ei, deg, E);
    k_scanA<<<SB, 256, 0, stream>>>(deg, bsum, N);
    k_scanB<<<1, 64, 0, stream>>>(bsum, boff, rp + N, SB);
    k_scanC<<<SB, 256, 0, stream>>>(deg, boff, rp, cur, N);
    k_fill<<<gE, 256, 0, stream>>>(ei, cur, csr, E);

    // ---- layer 1 ----
    k_gemm1<<<gG1, 256, 0, stream>>>(x, W1, as1, ad1, xw1b, al4, ar4, N);
    k_agg4<<<gB4, 256, 0, stream>>>(rp, csr, al4, ar4, xw1b, b1, W2, as2, ad2,
                                    xw2, al2, ar2, N);

    // ---- layer 2 ----
    k_agg2<<<gW, 256, 0, stream>>>(rp, csr, al2, ar2, xw2, b2v, out, N);

    // ---- pooling + logits ----
    hipMemsetAsync(pooled, 0, (NG * 64 + NG) * sizeof(float), stream);
    k_pool<<<gP, 256, 0, stream>>>(out, batch, pooled, cnt, N);
    k_logits<<<1, 64, 0, stream>>>(pooled, cnt, fcW, fcb, out + nv);
}